// Round 11
// baseline (613.441 us; speedup 1.0000x reference)
//
#include <hip/hip_runtime.h>

#define NN 50000
#define NE 800000
#define NG 50
#define NB 196    // ceil(NN/256)
#define NPB 391   // ceil(NN/128) pool blocks per branch

static constexpr float BN_EPS = 1e-5f;

typedef __attribute__((ext_vector_type(8))) short  bf16x8;
typedef __attribute__((ext_vector_type(8))) unsigned short u16x8;
typedef __attribute__((ext_vector_type(4))) float  f32x4;

// ---------------- bf16 helpers ----------------
__device__ __forceinline__ float bf2f(unsigned short u) {
    return __uint_as_float(((unsigned)u) << 16);
}
__device__ __forceinline__ unsigned short f2bf(float f) {
    unsigned u = __float_as_uint(f);
    unsigned r = (u + 0x7fffu + ((u >> 16) & 1u)) >> 16;   // RNE
    return (unsigned short)r;
}

// ---------------- degree / CSR build ----------------
__global__ void k_indeg(const int* __restrict__ dst, int* __restrict__ indeg) {
    int e = blockIdx.x * 256 + threadIdx.x;
    if (e < NE) atomicAdd(&indeg[dst[e]], 1);
}

__global__ void k_scan1(const int* __restrict__ cnt, int* __restrict__ rowstart,
                        int* __restrict__ bsum, float* __restrict__ dis) {
    int i = blockIdx.x * 256 + threadIdx.x;
    int lane = threadIdx.x & 63, wv = threadIdx.x >> 6;
    int v = (i < NN) ? cnt[i] : 0;
    if (i < NN) dis[i] = rsqrtf((float)v + 1.0f);
    int s = v;
#pragma unroll
    for (int d = 1; d < 64; d <<= 1) {
        int t = __shfl_up(s, d);
        if (lane >= d) s += t;
    }
    __shared__ int wtot[4];
    if (lane == 63) wtot[wv] = s;
    __syncthreads();
    int woff = 0;
    for (int w = 0; w < wv; ++w) woff += wtot[w];
    if (i < NN) rowstart[i] = woff + s - v;
    if (threadIdx.x == 255) bsum[blockIdx.x] = woff + s;
}

__global__ void k_scan2(const int* __restrict__ bsum, int* __restrict__ boff) {
    int lane = threadIdx.x & 63, wv = threadIdx.x >> 6;
    int v = (threadIdx.x < NB) ? bsum[threadIdx.x] : 0;
    int s = v;
#pragma unroll
    for (int d = 1; d < 64; d <<= 1) {
        int t = __shfl_up(s, d);
        if (lane >= d) s += t;
    }
    __shared__ int wtot[4];
    if (lane == 63) wtot[wv] = s;
    __syncthreads();
    int woff = 0;
    for (int w = 0; w < wv; ++w) woff += wtot[w];
    if (threadIdx.x < NB) boff[threadIdx.x] = woff + s - v;
}

__global__ void k_scan3(int* __restrict__ rowstart, const int* __restrict__ boff,
                        int* __restrict__ cursor) {
    int i = blockIdx.x * 256 + threadIdx.x;
    if (i < NN) {
        int v = rowstart[i] + boff[blockIdx.x];
        rowstart[i] = v;
        cursor[i] = v;
    }
    if (i == 0) rowstart[NN] = NE;
}

// 4B scatter (cheapest dirty-line form)
__global__ void k_fill(const int* __restrict__ src, const int* __restrict__ dst,
                       int* __restrict__ cursor, int* __restrict__ csr_src) {
    int e = blockIdx.x * 256 + threadIdx.x;
    if (e < NE) {
        int pos = atomicAdd(&cursor[dst[e]], 1);
        csr_src[pos] = src[e];
    }
}

// coalesced pack of {src, dis[src]} (r9's in-loop dis gather measured 1.7x worse)
__global__ void k_pack(const int* __restrict__ csr_src, const float* __restrict__ dis,
                       int2* __restrict__ pair) {
    int e = blockIdx.x * 256 + threadIdx.x;
    if (e < NE) {
        int s = csr_src[e];
        pair[e] = make_int2(s, __float_as_int(dis[s]));
    }
}

__global__ void k_count(const int* __restrict__ batch, float* __restrict__ cntG) {
    __shared__ int hist[NG];
    for (int i = threadIdx.x; i < NG; i += 256) hist[i] = 0;
    __syncthreads();
    for (int n = blockIdx.x * 256 + threadIdx.x; n < NN; n += gridDim.x * 256)
        atomicAdd(&hist[batch[n]], 1);
    __syncthreads();
    for (int i = threadIdx.x; i < NG; i += 256)
        if (hist[i]) atomicAdd(&cntG[i], (float)hist[i]);
}

// ---------------- weight conversion ----------------
struct WDesc { const float* s; unsigned short* d; int fin; int fout; };
struct WTable { WDesc w[12]; };

__global__ void k_convw(WTable t) {
    WDesc wd = t.w[blockIdx.x];
    int total = wd.fin * wd.fout;
    for (int i = threadIdx.x; i < total; i += 256) {
        int c = i / wd.fin, k = i % wd.fin;
        wd.d[i] = f2bf(wd.s[(size_t)k * wd.fout + c]);
    }
}

// ---------------- fused level-0 matmul: x(fp32) @ [gcn0|gat0|sWl0|sWr0] ------
__global__ __launch_bounds__(256) void k_mm0(
        const float* __restrict__ X, const unsigned short* __restrict__ Wf,
        const float* __restrict__ as_, const float* __restrict__ ad_,
        float* __restrict__ alsrc, float* __restrict__ aldst,
        unsigned short* __restrict__ comb, unsigned short* __restrict__ sr0) {
    constexpr int FIN = 128, NCT = 20;   // FOUT = 320
    int wave = threadIdx.x >> 6, lane = threadIdx.x & 63;
    int rowbase = (blockIdx.x * 4 + wave) * 16;
    if (rowbase >= NN) return;
    int lr = lane & 15, lg = lane >> 4;
    int arow = rowbase + lr;
    f32x4 acc[NCT] = {};
    const float* xp = X + (size_t)arow * FIN + lg * 8;
#pragma unroll
    for (int k0 = 0; k0 < FIN; k0 += 32) {
        float4 v0 = *(const float4*)(xp + k0);
        float4 v1 = *(const float4*)(xp + k0 + 4);
        u16x8 au;
        au[0] = f2bf(v0.x); au[1] = f2bf(v0.y); au[2] = f2bf(v0.z); au[3] = f2bf(v0.w);
        au[4] = f2bf(v1.x); au[5] = f2bf(v1.y); au[6] = f2bf(v1.z); au[7] = f2bf(v1.w);
        bf16x8 a1 = *(bf16x8*)&au;
#pragma unroll
        for (int ct = 0; ct < NCT; ++ct) {
            int wcol = ct * 16 + lr;
            bf16x8 b1 = *(const bf16x8*)(Wf + (size_t)wcol * FIN + k0 + lg * 8);
            acc[ct] = __builtin_amdgcn_mfma_f32_16x16x32_bf16(a1, b1, acc[ct], 0, 0, 0);
        }
    }
    // GAT attention-logit epilogue on fused cols 64..191
    {
        float ps[2][4] = {}, pd[2][4] = {};
#pragma unroll
        for (int ct = 4; ct < 12; ++ct) {
            int hh = (ct >= 8) ? 1 : 0;
            int colg = ct * 16 + lr - 64;
            float cs = as_[colg], cd = ad_[colg];
#pragma unroll
            for (int j = 0; j < 4; ++j) {
                ps[hh][j] += acc[ct][j] * cs;
                pd[hh][j] += acc[ct][j] * cd;
            }
        }
#pragma unroll
        for (int m = 1; m < 16; m <<= 1)
#pragma unroll
            for (int hh = 0; hh < 2; ++hh)
#pragma unroll
                for (int j = 0; j < 4; ++j) {
                    ps[hh][j] += __shfl_xor(ps[hh][j], m);
                    pd[hh][j] += __shfl_xor(pd[hh][j], m);
                }
        if (lr == 0) {
#pragma unroll
            for (int j = 0; j < 4; ++j) {
                int row = rowbase + lg * 4 + j;
#pragma unroll
                for (int hh = 0; hh < 2; ++hh) {
                    alsrc[(size_t)row * 2 + hh] = ps[hh][j];
                    aldst[(size_t)row * 2 + hh] = pd[hh][j];
                }
            }
        }
    }
#pragma unroll
    for (int ct = 0; ct < NCT; ++ct) {
        int col = ct * 16 + lr;
#pragma unroll
        for (int j = 0; j < 4; ++j) {
            int row = rowbase + lg * 4 + j;
            unsigned short v = f2bf(acc[ct][j]);
            if (ct < 4)       comb[(size_t)row * 256 + col] = v;              // GCN
            else if (ct < 12) comb[(size_t)row * 256 + 128 + (col - 64)] = v; // GAT
            else if (ct < 16) comb[(size_t)row * 256 + 64 + (col - 192)] = v; // SAGE-L
            else              sr0[(size_t)row * 64 + (col - 256)] = v;
        }
    }
}

// ---------------- MFMA matmul, 32 rows/wave, fused BN+act on A1 ------------
// BNACT: 0 none, 1 BN+relu, 2 BN+elu.  ALH: GAT logit epilogue heads.
template <int FIN, int FOUT, bool DUAL, bool BIAS, int BNACT, int ALH, int OSTR, int OOFF>
__global__ __launch_bounds__(256) void k_mm(
        const unsigned short* __restrict__ A1, const unsigned short* __restrict__ W1t,
        const unsigned short* __restrict__ A2, const unsigned short* __restrict__ W2t,
        const float* __restrict__ bias,
        const float* __restrict__ bns, const float* __restrict__ bng, const float* __restrict__ bnb,
        const float* __restrict__ as_, const float* __restrict__ ad_,
        float* __restrict__ alsrc, float* __restrict__ aldst,
        unsigned short* __restrict__ out) {
    constexpr int NCT = FOUT / 16;
    int wave = threadIdx.x >> 6, lane = threadIdx.x & 63;
    int rowbase = (blockIdx.x * 4 + wave) * 32;
    if (rowbase >= NN) return;
    bool t1 = (rowbase + 16) < NN;          // NN%32==16 -> last wave tile0 only
    int lr = lane & 15, lg = lane >> 4;
    int arow0 = rowbase + lr;
    int arow1 = t1 ? (arow0 + 16) : arow0;  // clamp (dup) when tile1 invalid
    f32x4 acc0[NCT] = {}, acc1[NCT] = {};
    const unsigned short* a1p0 = A1 + (size_t)arow0 * FIN + lg * 8;
    const unsigned short* a1p1 = A1 + (size_t)arow1 * FIN + lg * 8;
    const unsigned short* a2p0 = DUAL ? (A2 + (size_t)arow0 * FIN + lg * 8) : nullptr;
    const unsigned short* a2p1 = DUAL ? (A2 + (size_t)arow1 * FIN + lg * 8) : nullptr;
#pragma unroll
    for (int k0 = 0; k0 < FIN; k0 += 32) {
        bf16x8 a0, a1v;
        if (BNACT == 0) {
            a0  = *(const bf16x8*)(a1p0 + k0);
            a1v = *(const bf16x8*)(a1p1 + k0);
        } else {
            u16x8 r0v = *(const u16x8*)(a1p0 + k0);
            u16x8 r1v = *(const u16x8*)(a1p1 + k0);
            u16x8 t0, t1v;
#pragma unroll
            for (int j = 0; j < 8; ++j) {
                int f = k0 + lg * 8 + j;
                float mean = bns[f] * (1.0f / NN);
                float var = bns[FIN + f] * (1.0f / NN) - mean * mean;
                float rstd = rsqrtf(var + BN_EPS);
                float g = bng[f], bb = bnb[f];
                float v0 = (bf2f(r0v[j]) - mean) * rstd * g + bb;
                float v1 = (bf2f(r1v[j]) - mean) * rstd * g + bb;
                if (BNACT == 1) { v0 = fmaxf(v0, 0.f); v1 = fmaxf(v1, 0.f); }
                if (BNACT == 2) {
                    v0 = (v0 > 0.f) ? v0 : (__expf(v0) - 1.0f);
                    v1 = (v1 > 0.f) ? v1 : (__expf(v1) - 1.0f);
                }
                t0[j] = f2bf(v0); t1v[j] = f2bf(v1);
            }
            a0 = *(bf16x8*)&t0; a1v = *(bf16x8*)&t1v;
        }
        bf16x8 a20 = {}, a21 = {};
        if (DUAL) { a20 = *(const bf16x8*)(a2p0 + k0); a21 = *(const bf16x8*)(a2p1 + k0); }
#pragma unroll
        for (int ct = 0; ct < NCT; ++ct) {
            int wcol = ct * 16 + lr;
            bf16x8 b1 = *(const bf16x8*)(W1t + (size_t)wcol * FIN + k0 + lg * 8);
            acc0[ct] = __builtin_amdgcn_mfma_f32_16x16x32_bf16(a0, b1, acc0[ct], 0, 0, 0);
            acc1[ct] = __builtin_amdgcn_mfma_f32_16x16x32_bf16(a1v, b1, acc1[ct], 0, 0, 0);
            if (DUAL) {
                bf16x8 b2 = *(const bf16x8*)(W2t + (size_t)wcol * FIN + k0 + lg * 8);
                acc0[ct] = __builtin_amdgcn_mfma_f32_16x16x32_bf16(a20, b2, acc0[ct], 0, 0, 0);
                acc1[ct] = __builtin_amdgcn_mfma_f32_16x16x32_bf16(a21, b2, acc1[ct], 0, 0, 0);
            }
        }
    }
    if (ALH > 0) {
        constexpr int NH = (ALH > 0) ? ALH : 1;
        float ps0[NH][4] = {}, pd0[NH][4] = {}, ps1[NH][4] = {}, pd1[NH][4] = {};
#pragma unroll
        for (int ct = 0; ct < NCT; ++ct) {
            int hh = (ALH == 2 && ct >= NCT / 2) ? 1 : 0;
            int col = ct * 16 + lr;
            float cs = as_[col], cd = ad_[col];
#pragma unroll
            for (int j = 0; j < 4; ++j) {
                ps0[hh][j] += acc0[ct][j] * cs;
                pd0[hh][j] += acc0[ct][j] * cd;
                ps1[hh][j] += acc1[ct][j] * cs;
                pd1[hh][j] += acc1[ct][j] * cd;
            }
        }
#pragma unroll
        for (int m = 1; m < 16; m <<= 1)
#pragma unroll
            for (int hh = 0; hh < NH; ++hh)
#pragma unroll
                for (int j = 0; j < 4; ++j) {
                    ps0[hh][j] += __shfl_xor(ps0[hh][j], m);
                    pd0[hh][j] += __shfl_xor(pd0[hh][j], m);
                    ps1[hh][j] += __shfl_xor(ps1[hh][j], m);
                    pd1[hh][j] += __shfl_xor(pd1[hh][j], m);
                }
        if (lr == 0) {
#pragma unroll
            for (int j = 0; j < 4; ++j) {
                int row = rowbase + lg * 4 + j;
#pragma unroll
                for (int hh = 0; hh < NH; ++hh) {
                    alsrc[(size_t)row * ALH + hh] = ps0[hh][j];
                    aldst[(size_t)row * ALH + hh] = pd0[hh][j];
                    if (t1) {
                        alsrc[(size_t)(row + 16) * ALH + hh] = ps1[hh][j];
                        aldst[(size_t)(row + 16) * ALH + hh] = pd1[hh][j];
                    }
                }
            }
        }
    }
#pragma unroll
    for (int ct = 0; ct < NCT; ++ct) {
        int col = ct * 16 + lr;
        float bv = BIAS ? bias[col] : 0.f;
#pragma unroll
        for (int j = 0; j < 4; ++j) {
            int row = rowbase + lg * 4 + j;
            out[(size_t)row * OSTR + OOFF + col] = f2bf(acc0[ct][j] + bv);
            if (t1) out[(size_t)(row + 16) * OSTR + OOFF + col] = f2bf(acc1[ct][j] + bv);
        }
    }
}

// ---------------- fused 3-branch aggregation over comb[NN][256] -----------
// lane roles: fl 0-7 GCN, fl 8-15 SAGE, fl 16-31 GAT (head-aligned)
// r8 inner loop (int2 pair stream); THIS ROUND: unroll 4 -> 8, only change.
template <int H, bool GATBIAS>
__global__ __launch_bounds__(256) void k_aggf(
        const int* __restrict__ rowstart, const int2* __restrict__ pair,
        const float* __restrict__ dis, const float* __restrict__ alsrc,
        const float* __restrict__ aldst, const unsigned short* __restrict__ comb,
        const float* __restrict__ gat_bias,
        unsigned short* __restrict__ outGCN, unsigned short* __restrict__ outGAT,
        unsigned short* __restrict__ outSAGE) {
    int wave = threadIdx.x >> 6, lane = threadIdx.x & 63;
    int n = blockIdx.x * 4 + wave;
    if (n >= NN) return;
    int eg = lane >> 5, fl = lane & 31;
    int f0 = fl * 8;
    bool isGCN = fl < 8, isSAGE = (fl >= 8) && (fl < 16), isGAT = fl >= 16;
    int hh = (H == 2) ? ((fl >= 24) ? 1 : 0) : 0;
    int r0 = rowstart[n], r1 = rowstart[n + 1];
    float dn = dis[n];
    float adn = isGAT ? aldst[n * H + hh] : 0.f;
    float tself = isGAT ? (alsrc[n * H + hh] + adn) : 0.f;
    tself = (tself >= 0.f) ? tself : 0.2f * tself;
    float wsG = __expf(tself);                       // GAT self weight
    float selfw = isGCN ? dn * dn : (isGAT ? wsG : 0.f);
    float acc[8] = {};
    if (eg == 0) {
        u16x8 hv = *(const u16x8*)&comb[(size_t)n * 256 + f0];
#pragma unroll
        for (int j = 0; j < 8; ++j) acc[j] = selfw * bf2f(hv[j]);
    }
    float dsum = 0.f;
#pragma unroll 8
    for (int e = r0 + eg; e < r1; e += 2) {
        int2 p = pair[e];
        int s = p.x;
        float al = isGAT ? alsrc[(size_t)s * H + hh] : 0.f;
        float v = al + adn;
        v = (v >= 0.f) ? v : 0.2f * v;
        float we = __expf(v);
        dsum += we;
        float w = isGCN ? __int_as_float(p.y) * dn : (isGAT ? we : 1.0f);
        u16x8 hs = *(const u16x8*)&comb[(size_t)s * 256 + f0];
#pragma unroll
        for (int jj = 0; jj < 8; ++jj) acc[jj] += w * bf2f(hs[jj]);
    }
    // GAT denominator (masked butterfly within head cluster + cross-eg)
    if (H == 2) {
        dsum += __shfl_xor(dsum, 1);
        dsum += __shfl_xor(dsum, 2);
        dsum += __shfl_xor(dsum, 4);
        dsum += __shfl_xor(dsum, 32);
        dsum *= 0.125f;
    } else {
        dsum += __shfl_xor(dsum, 1);
        dsum += __shfl_xor(dsum, 2);
        dsum += __shfl_xor(dsum, 4);
        dsum += __shfl_xor(dsum, 8);
        dsum += __shfl_xor(dsum, 32);
        dsum *= 0.0625f;
    }
    float dinv = 1.0f / (wsG + dsum + 1e-16f);
    // feature reduce across the two edge-groups
#pragma unroll
    for (int jj = 0; jj < 8; ++jj) acc[jj] += __shfl_xor(acc[jj], 32);
    if (eg == 0) {
        float inv = 1.0f / fmaxf((float)(r1 - r0), 1.0f);
        float mul = isGCN ? 1.0f : (isSAGE ? inv : dinv);
        u16x8 o;
#pragma unroll
        for (int jj = 0; jj < 8; ++jj) {
            float v = acc[jj] * mul;
            if (GATBIAS && isGAT) v += gat_bias[f0 - 128 + jj];
            o[jj] = f2bf(v);
        }
        if (isGCN)       *(u16x8*)&outGCN[(size_t)n * 64 + f0] = o;
        else if (isSAGE) *(u16x8*)&outSAGE[(size_t)n * 64 + (f0 - 64)] = o;
        else             *(u16x8*)&outGAT[(size_t)n * 128 + (f0 - 128)] = o;
    }
}

// ---------------- fused 3-buffer BatchNorm stats ----------------
// octet roles: 0-7 GCN(64), 8-23 GAT(128), 24-31 SAGE(64, +sr if TWO)
template <bool SAGEON, bool TWO>
__global__ void k_bn_stats3(const unsigned short* __restrict__ gcn,
                            const unsigned short* __restrict__ gat,
                            const unsigned short* __restrict__ sage,
                            const unsigned short* __restrict__ sr,
                            float* __restrict__ segG, float* __restrict__ segA,
                            float* __restrict__ segS) {
    __shared__ float lsum[256], lsq[256];
    for (int i = threadIdx.x; i < 256; i += 256) { lsum[i] = 0.f; lsq[i] = 0.f; }
    __syncthreads();
    int oct = threadIdx.x & 31, rl = threadIdx.x >> 5;   // 8 row-lanes
    if (SAGEON || oct < 24) {
        float s[8] = {}, s2[8] = {};
        for (int n = blockIdx.x * 8 + rl; n < NN; n += gridDim.x * 8) {
            u16x8 v;
            if (oct < 8)       v = *(const u16x8*)&gcn[(size_t)n * 64 + oct * 8];
            else if (oct < 24) v = *(const u16x8*)&gat[(size_t)n * 128 + (oct - 8) * 8];
            else               v = *(const u16x8*)&sage[(size_t)n * 64 + (oct - 24) * 8];
            u16x8 w = {};
            if (TWO && oct >= 24) w = *(const u16x8*)&sr[(size_t)n * 64 + (oct - 24) * 8];
#pragma unroll
            for (int j = 0; j < 8; ++j) {
                float f = bf2f(v[j]);
                if (TWO && oct >= 24) f += bf2f(w[j]);
                s[j] += f; s2[j] += f * f;
            }
        }
#pragma unroll
        for (int j = 0; j < 8; ++j) {
            atomicAdd(&lsum[oct * 8 + j], s[j]);
            atomicAdd(&lsq[oct * 8 + j], s2[j]);
        }
    }
    __syncthreads();
    int t = threadIdx.x;
    if (t < 192 || SAGEON) {
        float* base; int f, F;
        if (t < 64)       { base = segG; f = t;       F = 64; }
        else if (t < 192) { base = segA; f = t - 64;  F = 128; }
        else              { base = segS; f = t - 192; F = 64; }
        atomicAdd(&base[f], lsum[t]);
        atomicAdd(&base[F + f], lsq[t]);
    }
}

// ---------------- single-buffer BatchNorm stats (sageM1) -------------------
template <int F, bool TWO>
__global__ void k_bn_stats(const unsigned short* __restrict__ x,
                           const unsigned short* __restrict__ y,
                           float* __restrict__ sums) {
    constexpr int TPR = F / 8;
    constexpr int RPB = 256 / TPR;
    __shared__ float lsum[F], lsq[F];
    for (int i = threadIdx.x; i < F; i += 256) { lsum[i] = 0.f; lsq[i] = 0.f; }
    __syncthreads();
    int fl = threadIdx.x % TPR, rl = threadIdx.x / TPR;
    int f0 = fl * 8;
    float s[8] = {}, s2[8] = {};
    for (int n = blockIdx.x * RPB + rl; n < NN; n += gridDim.x * RPB) {
        u16x8 v = *(const u16x8*)&x[(size_t)n * F + f0];
        u16x8 w = {};
        if (TWO) w = *(const u16x8*)&y[(size_t)n * F + f0];
#pragma unroll
        for (int j = 0; j < 8; ++j) {
            float f = bf2f(v[j]);
            if (TWO) f += bf2f(w[j]);
            s[j] += f; s2[j] += f * f;
        }
    }
#pragma unroll
    for (int off = TPR; off < 64; off <<= 1)
#pragma unroll
        for (int j = 0; j < 8; ++j) { s[j] += __shfl_xor(s[j], off); s2[j] += __shfl_xor(s2[j], off); }
    if ((threadIdx.x & 63) < TPR) {
#pragma unroll
        for (int j = 0; j < 8; ++j) {
            atomicAdd(&lsum[f0 + j], s[j]);
            atomicAdd(&lsq[f0 + j], s2[j]);
        }
    }
    __syncthreads();
    for (int i = threadIdx.x; i < F; i += 256) {
        atomicAdd(&sums[i], lsum[i]);
        atomicAdd(&sums[F + i], lsq[i]);
    }
}

// ---------------- BatchNorm apply, optional dual output --------------------
template <int F, int ACT, bool TWO, bool O1, bool O2, int OOFF>
__global__ void k_bn_apply(const unsigned short* __restrict__ x,
                           const unsigned short* __restrict__ y,
                           const float* __restrict__ sums,
                           const float* __restrict__ gamma, const float* __restrict__ beta,
                           unsigned short* __restrict__ out1, unsigned short* __restrict__ comb) {
    int idx = blockIdx.x * 256 + threadIdx.x;   // units of 8 elems
    if (idx >= NN * F / 8) return;
    int row = idx / (F / 8);
    int f0 = (idx % (F / 8)) * 8;
    u16x8 v = *(const u16x8*)&x[(size_t)idx * 8];
    u16x8 w = {};
    if (TWO) w = *(const u16x8*)&y[(size_t)idx * 8];
    u16x8 o;
#pragma unroll
    for (int j = 0; j < 8; ++j) {
        int f = f0 + j;
        float mean = sums[f] * (1.0f / NN);
        float var = sums[F + f] * (1.0f / NN) - mean * mean;
        float rstd = rsqrtf(var + BN_EPS);
        float raw = bf2f(v[j]);
        if (TWO) raw += bf2f(w[j]);
        float val = (raw - mean) * rstd * gamma[f] + beta[f];
        if (ACT == 1) val = fmaxf(val, 0.f);
        if (ACT == 2) val = (val > 0.f) ? val : (__expf(val) - 1.0f);
        o[j] = f2bf(val);
    }
    if (O1) *(u16x8*)&out1[(size_t)idx * 8] = o;
    if (O2) *(u16x8*)&comb[(size_t)row * 256 + OOFF + f0] = o;
}

// ---------------- pooling (all three branches, one dispatch) ---------------
__global__ void k_pool3(const unsigned short* __restrict__ a,
                        const unsigned short* __restrict__ b,
                        const unsigned short* __restrict__ c,
                        const int* __restrict__ batch, float* __restrict__ pooled) {
    int sel = blockIdx.x / NPB;
    int nb = blockIdx.x % NPB;
    const unsigned short* x = (sel == 0) ? a : ((sel == 1) ? b : c);
    int off = sel * 128;
    int f = threadIdx.x & 127;
    int half = threadIdx.x >> 7;
    int nend = min(NN, (nb + 1) * 128);
    float acc = 0.f; int gcur = -1;
    for (int n = nb * 128 + half; n < nend; n += 2) {
        int g = batch[n];
        if (g != gcur) {
            if (gcur >= 0) atomicAdd(&pooled[(size_t)gcur * 384 + off + f], acc);
            gcur = g; acc = 0.f;
        }
        acc += bf2f(x[(size_t)n * 128 + f]);
    }
    if (gcur >= 0) atomicAdd(&pooled[(size_t)gcur * 384 + off + f], acc);
}

__global__ void k_fusion(const float* __restrict__ pooled, const float* __restrict__ cntG,
                         const float* __restrict__ W, const float* __restrict__ b,
                         float* __restrict__ out) {
    int idx = blockIdx.x * 256 + threadIdx.x;   // NG*128
    if (idx >= NG * 128) return;
    int g = idx / 128, o = idx % 128;
    float inv = 1.0f / fmaxf(cntG[g], 1.0f);
    float acc = b[o];
#pragma unroll 4
    for (int k = 0; k < 384; ++k)
        acc += pooled[g * 384 + k] * inv * W[k * 128 + o];
    out[idx] = acc;
}

// ---------------- launcher ----------------
static inline int grid1(long long n) { return (int)((n + 255) / 256); }

extern "C" void kernel_launch(void* const* d_in, const int* in_sizes, int n_in,
                              void* d_out, int out_size, void* d_ws, size_t ws_size,
                              hipStream_t stream) {
    const float* x       = (const float*)d_in[0];
    const int*   ei      = (const int*)d_in[1];
    const int*   batch   = (const int*)d_in[2];
    const float* gcn_W0  = (const float*)d_in[3];
    const float* gcn_W1  = (const float*)d_in[5];
    const float* gcn_W2  = (const float*)d_in[7];
    const float* gcn_b2  = (const float*)d_in[8];
    const float* gcn_g0  = (const float*)d_in[9];
    const float* gcn_bb0 = (const float*)d_in[10];
    const float* gcn_g1  = (const float*)d_in[11];
    const float* gcn_bb1 = (const float*)d_in[12];
    const float* gat_W0  = (const float*)d_in[13];
    const float* gat_as0 = (const float*)d_in[14];
    const float* gat_ad0 = (const float*)d_in[15];
    const float* gat_W1  = (const float*)d_in[17];
    const float* gat_as1 = (const float*)d_in[18];
    const float* gat_ad1 = (const float*)d_in[19];
    const float* gat_W2  = (const float*)d_in[21];
    const float* gat_as2 = (const float*)d_in[22];
    const float* gat_ad2 = (const float*)d_in[23];
    const float* gat_b2  = (const float*)d_in[24];
    const float* gat_g0  = (const float*)d_in[25];
    const float* gat_bb0 = (const float*)d_in[26];
    const float* gat_g1  = (const float*)d_in[27];
    const float* gat_bb1 = (const float*)d_in[28];
    const float* sage_Wl0 = (const float*)d_in[29];
    const float* sage_Wr0 = (const float*)d_in[30];
    const float* sage_Wl1 = (const float*)d_in[32];
    const float* sage_Wr1 = (const float*)d_in[33];
    const float* sage_Wl2 = (const float*)d_in[35];
    const float* sage_Wr2 = (const float*)d_in[36];
    const float* sage_b2  = (const float*)d_in[37];
    const float* sage_g0  = (const float*)d_in[38];
    const float* sage_bb0 = (const float*)d_in[39];
    const float* sage_g1  = (const float*)d_in[40];
    const float* sage_bb1 = (const float*)d_in[41];
    const float* fus_W    = (const float*)d_in[42];
    const float* fus_b    = (const float*)d_in[43];

    const int* src = ei;
    const int* dst = ei + NE;

    // workspace layout (float units)
    float* ws = (float*)d_ws;
    size_t off = 0;
    auto alloc = [&](size_t n) { float* p = ws + off; off += (n + 3) & ~(size_t)3; return p; };
    unsigned short* combA = (unsigned short*)alloc((size_t)NN * 128);  // NN*256 bf16
    unsigned short* combB = (unsigned short*)alloc((size_t)NN * 128);
    unsigned short* bufGCN  = (unsigned short*)alloc((size_t)NN * 32); // NN*64 bf16
    unsigned short* bufGAT  = (unsigned short*)alloc((size_t)NN * 64); // NN*128 bf16
    unsigned short* bufSAGE = (unsigned short*)alloc((size_t)NN * 32);
    unsigned short* sr0     = (unsigned short*)alloc((size_t)NN * 32);
    unsigned short* sageH0  = (unsigned short*)alloc((size_t)NN * 32);
    unsigned short* sageM1  = (unsigned short*)alloc((size_t)NN * 32);
    unsigned short* wt      = (unsigned short*)alloc(110592 / 2);
    int*   rowstart = (int*)alloc(NN + 1);
    int*   cursor   = (int*)alloc(NN);
    int*   csr_src  = (int*)alloc(NE);
    int2*  pair     = (int2*)alloc((size_t)NE * 2);
    int*   bsum     = (int*)alloc(NB);
    int*   boff     = (int*)alloc(NB);
    float* dis   = alloc(NN);
    float* alsrc = alloc((size_t)NN * 2);
    float* aldst = alloc((size_t)NN * 2);
    // contiguous zero region: bnsum | pooled | cntG | indeg
    float* zr = alloc(6 * 256 + NG * 384 + NG + NN);
    float* bnsum  = zr;
    float* pooled = bnsum + 6 * 256;
    float* cntG   = pooled + NG * 384;
    int*   indeg  = (int*)(cntG + NG);
    (void)ws_size; (void)n_in; (void)in_sizes; (void)out_size;

    unsigned short* sageH1  = sr0;                    // sr0 dead after L0
    unsigned short* finGCN  = combB;                  // combB dead after aggF L1
    unsigned short* finSAGE = combB + (size_t)NN * 128;

    // fused L0 weights [gcn(64)|gat(128)|sWl(64)|sWr(64)] x 128 + per-layer W^T
    unsigned short* wf        = wt;                  // 40960
    unsigned short* gcn_W1t   = wf + 40960;          // 64x64
    unsigned short* gcn_W2t   = gcn_W1t + 4096;      // 64x128
    unsigned short* gat_W1t   = gcn_W2t + 8192;      // 128x128
    unsigned short* gat_W2t   = gat_W1t + 16384;
    unsigned short* sage_Wl1t = gat_W2t + 16384;
    unsigned short* sage_Wr1t = sage_Wl1t + 4096;
    unsigned short* sage_Wl2t = sage_Wr1t + 4096;
    unsigned short* sage_Wr2t = sage_Wl2t + 8192;

    const int gAgg = NN / 4;
    const int gMM  = (NN + 63) / 64;     // k_mm0: 16 rows/wave
    const int gMM2 = (NN + 127) / 128;   // k_mm:  32 rows/wave

    // ---- CSR build + precompute ----
    hipMemsetAsync(zr, 0, (6 * 256 + NG * 384 + NG + NN) * 4, stream);
    k_indeg<<<grid1(NE), 256, 0, stream>>>(dst, indeg);
    k_scan1<<<NB, 256, 0, stream>>>(indeg, rowstart, bsum, dis);
    k_scan2<<<1, 256, 0, stream>>>(bsum, boff);
    k_scan3<<<NB, 256, 0, stream>>>(rowstart, boff, cursor);
    k_fill<<<grid1(NE), 256, 0, stream>>>(src, dst, cursor, csr_src);
    k_pack<<<grid1(NE), 256, 0, stream>>>(csr_src, dis, pair);
    k_count<<<128, 256, 0, stream>>>(batch, cntG);
    WTable wtab = {{
        { gcn_W0, wf, 128, 64 }, { gat_W0, wf + 64 * 128, 128, 128 },
        { sage_Wl0, wf + 192 * 128, 128, 64 }, { sage_Wr0, wf + 256 * 128, 128, 64 },
        { gcn_W1, gcn_W1t, 64, 64 }, { gcn_W2, gcn_W2t, 64, 128 },
        { gat_W1, gat_W1t, 128, 128 }, { gat_W2, gat_W2t, 128, 128 },
        { sage_Wl1, sage_Wl1t, 64, 64 }, { sage_Wr1, sage_Wr1t, 64, 64 },
        { sage_Wl2, sage_Wl2t, 64, 128 }, { sage_Wr2, sage_Wr2t, 64, 128 },
    }};
    k_convw<<<12, 256, 0, stream>>>(wtab);

    // ---- L0: fused matmul -> combA; fused agg -> compacts ----
    k_mm0<<<gMM, 256, 0, stream>>>(x, wf, gat_as0, gat_ad0, alsrc, aldst, combA, sr0);
    k_aggf<2, false><<<gAgg, 256, 0, stream>>>(rowstart, pair, dis, alsrc, aldst,
                                               combA, nullptr, bufGCN, bufGAT, bufSAGE);
    k_bn_stats3<true, true><<<250, 256, 0, stream>>>(
        bufGCN, bufGAT, bufSAGE, sr0, bnsum + 0 * 256, bnsum + 2 * 256, bnsum + 4 * 256);
    // L1 producers -> combB
    k_mm<64, 64, false, false, 1, 0, 256, 0><<<gMM2, 256, 0, stream>>>(
        bufGCN, gcn_W1t, nullptr, nullptr, nullptr,
        bnsum + 0 * 256, gcn_g0, gcn_bb0, nullptr, nullptr, nullptr, nullptr, combB);
    k_mm<128, 128, false, false, 2, 2, 256, 128><<<gMM2, 256, 0, stream>>>(
        bufGAT, gat_W1t, nullptr, nullptr, nullptr,
        bnsum + 2 * 256, gat_g0, gat_bb0, gat_as1, gat_ad1, alsrc, aldst, combB);
    k_bn_apply<64, 1, true, true, true, 64><<<grid1(NN * 8), 256, 0, stream>>>(
        bufSAGE, sr0, bnsum + 4 * 256, sage_g0, sage_bb0, sageH0, combB);

    // ---- L1: fused agg ----
    k_aggf<2, false><<<gAgg, 256, 0, stream>>>(rowstart, pair, dis, alsrc, aldst,
                                               combB, nullptr, bufGCN, bufGAT, bufSAGE);
    k_bn_stats3<false, false><<<250, 256, 0, stream>>>(
        bufGCN, bufGAT, nullptr, nullptr, bnsum + 1 * 256, bnsum + 3 * 256, nullptr);
    k_mm<64, 64, true, false, 0, 0, 64, 0><<<gMM2, 256, 0, stream>>>(
        bufSAGE, sage_Wl1t, sageH0, sage_Wr1t, nullptr,
        nullptr, nullptr, nullptr, nullptr, nullptr, nullptr, nullptr, sageM1);
    // L2 producers -> combA
    k_bn_apply<64, 1, false, false, true, 0><<<grid1(NN * 8), 256, 0, stream>>>(
        bufGCN, nullptr, bnsum + 1 * 256, gcn_g1, gcn_bb1, nullptr, combA);
    k_mm<128, 128, false, false, 2, 1, 256, 128><<<gMM2, 256, 0, stream>>>(
        bufGAT, gat_W2t, nullptr, nullptr, nullptr,
        bnsum + 3 * 256, gat_g1, gat_bb1, gat_as2, gat_ad2, alsrc, aldst, combA);
    k_bn_stats<64, false><<<250, 256, 0, stream>>>(sageM1, nullptr, bnsum + 5 * 256);
    k_bn_apply<64, 1, false, true, true, 64><<<grid1(NN * 8), 256, 0, stream>>>(
        sageM1, nullptr, bnsum + 5 * 256, sage_g1, sage_bb1, sageH1, combA);

    // ---- L2: fused agg (GAT H=1, bias fused) ----
    k_aggf<1, true><<<gAgg, 256, 0, stream>>>(rowstart, pair, dis, alsrc, aldst,
                                              combA, gat_b2, bufGCN, bufGAT, bufSAGE);
    k_mm<64, 128, false, true, 0, 0, 128, 0><<<gMM2, 256, 0, stream>>>(
        bufGCN, gcn_W2t, nullptr, nullptr, gcn_b2,
        nullptr, nullptr, nullptr, nullptr, nullptr, nullptr, nullptr, finGCN);
    k_mm<64, 128, true, true, 0, 0, 128, 0><<<gMM2, 256, 0, stream>>>(
        bufSAGE, sage_Wl2t, sageH1, sage_Wr2t, sage_b2,
        nullptr, nullptr, nullptr, nullptr, nullptr, nullptr, nullptr, finSAGE);

    // ---- pool + fusion ----
    k_pool3<<<3 * NPB, 256, 0, stream>>>(finGCN, bufGAT, finSAGE, batch, pooled);
    k_fusion<<<grid1(NG * 128), 256, 0, stream>>>(pooled, cntG, fus_W, fus_b, (float*)d_out);
}

// Round 12
// 592.101 us; speedup vs baseline: 1.0360x; 1.0360x over previous
//
#include <hip/hip_runtime.h>

#define NN 50000
#define NE 800000
#define NG 50
#define NB 196    // ceil(NN/256)
#define NPB 391   // ceil(NN/128) pool blocks per branch

static constexpr float BN_EPS = 1e-5f;

typedef __attribute__((ext_vector_type(8))) short  bf16x8;
typedef __attribute__((ext_vector_type(8))) unsigned short u16x8;
typedef __attribute__((ext_vector_type(4))) float  f32x4;

// ---------------- bf16 helpers ----------------
__device__ __forceinline__ float bf2f(unsigned short u) {
    return __uint_as_float(((unsigned)u) << 16);
}
__device__ __forceinline__ unsigned short f2bf(float f) {
    unsigned u = __float_as_uint(f);
    unsigned r = (u + 0x7fffu + ((u >> 16) & 1u)) >> 16;   // RNE
    return (unsigned short)r;
}

// ---------------- degree / CSR build ----------------
__global__ void k_indeg(const int* __restrict__ dst, int* __restrict__ indeg) {
    int e = blockIdx.x * 256 + threadIdx.x;
    if (e < NE) atomicAdd(&indeg[dst[e]], 1);
}

__global__ void k_scan1(const int* __restrict__ cnt, int* __restrict__ rowstart,
                        int* __restrict__ bsum, float* __restrict__ dis) {
    int i = blockIdx.x * 256 + threadIdx.x;
    int lane = threadIdx.x & 63, wv = threadIdx.x >> 6;
    int v = (i < NN) ? cnt[i] : 0;
    if (i < NN) dis[i] = rsqrtf((float)v + 1.0f);
    int s = v;
#pragma unroll
    for (int d = 1; d < 64; d <<= 1) {
        int t = __shfl_up(s, d);
        if (lane >= d) s += t;
    }
    __shared__ int wtot[4];
    if (lane == 63) wtot[wv] = s;
    __syncthreads();
    int woff = 0;
    for (int w = 0; w < wv; ++w) woff += wtot[w];
    if (i < NN) rowstart[i] = woff + s - v;
    if (threadIdx.x == 255) bsum[blockIdx.x] = woff + s;
}

__global__ void k_scan2(const int* __restrict__ bsum, int* __restrict__ boff) {
    int lane = threadIdx.x & 63, wv = threadIdx.x >> 6;
    int v = (threadIdx.x < NB) ? bsum[threadIdx.x] : 0;
    int s = v;
#pragma unroll
    for (int d = 1; d < 64; d <<= 1) {
        int t = __shfl_up(s, d);
        if (lane >= d) s += t;
    }
    __shared__ int wtot[4];
    if (lane == 63) wtot[wv] = s;
    __syncthreads();
    int woff = 0;
    for (int w = 0; w < wv; ++w) woff += wtot[w];
    if (threadIdx.x < NB) boff[threadIdx.x] = woff + s - v;
}

__global__ void k_scan3(int* __restrict__ rowstart, const int* __restrict__ boff,
                        int* __restrict__ cursor) {
    int i = blockIdx.x * 256 + threadIdx.x;
    if (i < NN) {
        int v = rowstart[i] + boff[blockIdx.x];
        rowstart[i] = v;
        cursor[i] = v;
    }
    if (i == 0) rowstart[NN] = NE;
}

// 4B scatter (cheapest dirty-line form)
__global__ void k_fill(const int* __restrict__ src, const int* __restrict__ dst,
                       int* __restrict__ cursor, int* __restrict__ csr_src) {
    int e = blockIdx.x * 256 + threadIdx.x;
    if (e < NE) {
        int pos = atomicAdd(&cursor[dst[e]], 1);
        csr_src[pos] = src[e];
    }
}

// coalesced pack of {src, dis[src]} (r9's in-loop dis gather measured 1.7x worse)
__global__ void k_pack(const int* __restrict__ csr_src, const float* __restrict__ dis,
                       int2* __restrict__ pair) {
    int e = blockIdx.x * 256 + threadIdx.x;
    if (e < NE) {
        int s = csr_src[e];
        pair[e] = make_int2(s, __float_as_int(dis[s]));
    }
}

__global__ void k_count(const int* __restrict__ batch, float* __restrict__ cntG) {
    __shared__ int hist[NG];
    for (int i = threadIdx.x; i < NG; i += 256) hist[i] = 0;
    __syncthreads();
    for (int n = blockIdx.x * 256 + threadIdx.x; n < NN; n += gridDim.x * 256)
        atomicAdd(&hist[batch[n]], 1);
    __syncthreads();
    for (int i = threadIdx.x; i < NG; i += 256)
        if (hist[i]) atomicAdd(&cntG[i], (float)hist[i]);
}

// ---------------- weight conversion ----------------
struct WDesc { const float* s; unsigned short* d; int fin; int fout; };
struct WTable { WDesc w[12]; };

__global__ void k_convw(WTable t) {
    WDesc wd = t.w[blockIdx.x];
    int total = wd.fin * wd.fout;
    for (int i = threadIdx.x; i < total; i += 256) {
        int c = i / wd.fin, k = i % wd.fin;
        wd.d[i] = f2bf(wd.s[(size_t)k * wd.fout + c]);
    }
}

// ---------------- fused level-0 matmul: x(fp32) @ [gcn0|gat0|sWl0|sWr0] ------
__global__ __launch_bounds__(256) void k_mm0(
        const float* __restrict__ X, const unsigned short* __restrict__ Wf,
        const float* __restrict__ as_, const float* __restrict__ ad_,
        float* __restrict__ alsrc, float* __restrict__ aldst,
        unsigned short* __restrict__ comb, unsigned short* __restrict__ sr0) {
    constexpr int FIN = 128, NCT = 20;   // FOUT = 320
    int wave = threadIdx.x >> 6, lane = threadIdx.x & 63;
    int rowbase = (blockIdx.x * 4 + wave) * 16;
    if (rowbase >= NN) return;
    int lr = lane & 15, lg = lane >> 4;
    int arow = rowbase + lr;
    f32x4 acc[NCT] = {};
    const float* xp = X + (size_t)arow * FIN + lg * 8;
#pragma unroll
    for (int k0 = 0; k0 < FIN; k0 += 32) {
        float4 v0 = *(const float4*)(xp + k0);
        float4 v1 = *(const float4*)(xp + k0 + 4);
        u16x8 au;
        au[0] = f2bf(v0.x); au[1] = f2bf(v0.y); au[2] = f2bf(v0.z); au[3] = f2bf(v0.w);
        au[4] = f2bf(v1.x); au[5] = f2bf(v1.y); au[6] = f2bf(v1.z); au[7] = f2bf(v1.w);
        bf16x8 a1 = *(bf16x8*)&au;
#pragma unroll
        for (int ct = 0; ct < NCT; ++ct) {
            int wcol = ct * 16 + lr;
            bf16x8 b1 = *(const bf16x8*)(Wf + (size_t)wcol * FIN + k0 + lg * 8);
            acc[ct] = __builtin_amdgcn_mfma_f32_16x16x32_bf16(a1, b1, acc[ct], 0, 0, 0);
        }
    }
    // GAT attention-logit epilogue on fused cols 64..191
    {
        float ps[2][4] = {}, pd[2][4] = {};
#pragma unroll
        for (int ct = 4; ct < 12; ++ct) {
            int hh = (ct >= 8) ? 1 : 0;
            int colg = ct * 16 + lr - 64;
            float cs = as_[colg], cd = ad_[colg];
#pragma unroll
            for (int j = 0; j < 4; ++j) {
                ps[hh][j] += acc[ct][j] * cs;
                pd[hh][j] += acc[ct][j] * cd;
            }
        }
#pragma unroll
        for (int m = 1; m < 16; m <<= 1)
#pragma unroll
            for (int hh = 0; hh < 2; ++hh)
#pragma unroll
                for (int j = 0; j < 4; ++j) {
                    ps[hh][j] += __shfl_xor(ps[hh][j], m);
                    pd[hh][j] += __shfl_xor(pd[hh][j], m);
                }
        if (lr == 0) {
#pragma unroll
            for (int j = 0; j < 4; ++j) {
                int row = rowbase + lg * 4 + j;
#pragma unroll
                for (int hh = 0; hh < 2; ++hh) {
                    alsrc[(size_t)row * 2 + hh] = ps[hh][j];
                    aldst[(size_t)row * 2 + hh] = pd[hh][j];
                }
            }
        }
    }
#pragma unroll
    for (int ct = 0; ct < NCT; ++ct) {
        int col = ct * 16 + lr;
#pragma unroll
        for (int j = 0; j < 4; ++j) {
            int row = rowbase + lg * 4 + j;
            unsigned short v = f2bf(acc[ct][j]);
            if (ct < 4)       comb[(size_t)row * 256 + col] = v;              // GCN
            else if (ct < 12) comb[(size_t)row * 256 + 128 + (col - 64)] = v; // GAT
            else if (ct < 16) comb[(size_t)row * 256 + 64 + (col - 192)] = v; // SAGE-L
            else              sr0[(size_t)row * 64 + (col - 256)] = v;
        }
    }
}

// ---------------- MFMA matmul, 32 rows/wave, fused BN+act on A1 ------------
// BNACT: 0 none, 1 BN+relu, 2 BN+elu.  ALH: GAT logit epilogue heads.
template <int FIN, int FOUT, bool DUAL, bool BIAS, int BNACT, int ALH, int OSTR, int OOFF>
__global__ __launch_bounds__(256) void k_mm(
        const unsigned short* __restrict__ A1, const unsigned short* __restrict__ W1t,
        const unsigned short* __restrict__ A2, const unsigned short* __restrict__ W2t,
        const float* __restrict__ bias,
        const float* __restrict__ bns, const float* __restrict__ bng, const float* __restrict__ bnb,
        const float* __restrict__ as_, const float* __restrict__ ad_,
        float* __restrict__ alsrc, float* __restrict__ aldst,
        unsigned short* __restrict__ out) {
    constexpr int NCT = FOUT / 16;
    int wave = threadIdx.x >> 6, lane = threadIdx.x & 63;
    int rowbase = (blockIdx.x * 4 + wave) * 32;
    if (rowbase >= NN) return;
    bool t1 = (rowbase + 16) < NN;          // NN%32==16 -> last wave tile0 only
    int lr = lane & 15, lg = lane >> 4;
    int arow0 = rowbase + lr;
    int arow1 = t1 ? (arow0 + 16) : arow0;  // clamp (dup) when tile1 invalid
    f32x4 acc0[NCT] = {}, acc1[NCT] = {};
    const unsigned short* a1p0 = A1 + (size_t)arow0 * FIN + lg * 8;
    const unsigned short* a1p1 = A1 + (size_t)arow1 * FIN + lg * 8;
    const unsigned short* a2p0 = DUAL ? (A2 + (size_t)arow0 * FIN + lg * 8) : nullptr;
    const unsigned short* a2p1 = DUAL ? (A2 + (size_t)arow1 * FIN + lg * 8) : nullptr;
#pragma unroll
    for (int k0 = 0; k0 < FIN; k0 += 32) {
        bf16x8 a0, a1v;
        if (BNACT == 0) {
            a0  = *(const bf16x8*)(a1p0 + k0);
            a1v = *(const bf16x8*)(a1p1 + k0);
        } else {
            u16x8 r0v = *(const u16x8*)(a1p0 + k0);
            u16x8 r1v = *(const u16x8*)(a1p1 + k0);
            u16x8 t0, t1v;
#pragma unroll
            for (int j = 0; j < 8; ++j) {
                int f = k0 + lg * 8 + j;
                float mean = bns[f] * (1.0f / NN);
                float var = bns[FIN + f] * (1.0f / NN) - mean * mean;
                float rstd = rsqrtf(var + BN_EPS);
                float g = bng[f], bb = bnb[f];
                float v0 = (bf2f(r0v[j]) - mean) * rstd * g + bb;
                float v1 = (bf2f(r1v[j]) - mean) * rstd * g + bb;
                if (BNACT == 1) { v0 = fmaxf(v0, 0.f); v1 = fmaxf(v1, 0.f); }
                if (BNACT == 2) {
                    v0 = (v0 > 0.f) ? v0 : (__expf(v0) - 1.0f);
                    v1 = (v1 > 0.f) ? v1 : (__expf(v1) - 1.0f);
                }
                t0[j] = f2bf(v0); t1v[j] = f2bf(v1);
            }
            a0 = *(bf16x8*)&t0; a1v = *(bf16x8*)&t1v;
        }
        bf16x8 a20 = {}, a21 = {};
        if (DUAL) { a20 = *(const bf16x8*)(a2p0 + k0); a21 = *(const bf16x8*)(a2p1 + k0); }
#pragma unroll
        for (int ct = 0; ct < NCT; ++ct) {
            int wcol = ct * 16 + lr;
            bf16x8 b1 = *(const bf16x8*)(W1t + (size_t)wcol * FIN + k0 + lg * 8);
            acc0[ct] = __builtin_amdgcn_mfma_f32_16x16x32_bf16(a0, b1, acc0[ct], 0, 0, 0);
            acc1[ct] = __builtin_amdgcn_mfma_f32_16x16x32_bf16(a1v, b1, acc1[ct], 0, 0, 0);
            if (DUAL) {
                bf16x8 b2 = *(const bf16x8*)(W2t + (size_t)wcol * FIN + k0 + lg * 8);
                acc0[ct] = __builtin_amdgcn_mfma_f32_16x16x32_bf16(a20, b2, acc0[ct], 0, 0, 0);
                acc1[ct] = __builtin_amdgcn_mfma_f32_16x16x32_bf16(a21, b2, acc1[ct], 0, 0, 0);
            }
        }
    }
    if (ALH > 0) {
        constexpr int NH = (ALH > 0) ? ALH : 1;
        float ps0[NH][4] = {}, pd0[NH][4] = {}, ps1[NH][4] = {}, pd1[NH][4] = {};
#pragma unroll
        for (int ct = 0; ct < NCT; ++ct) {
            int hh = (ALH == 2 && ct >= NCT / 2) ? 1 : 0;
            int col = ct * 16 + lr;
            float cs = as_[col], cd = ad_[col];
#pragma unroll
            for (int j = 0; j < 4; ++j) {
                ps0[hh][j] += acc0[ct][j] * cs;
                pd0[hh][j] += acc0[ct][j] * cd;
                ps1[hh][j] += acc1[ct][j] * cs;
                pd1[hh][j] += acc1[ct][j] * cd;
            }
        }
#pragma unroll
        for (int m = 1; m < 16; m <<= 1)
#pragma unroll
            for (int hh = 0; hh < NH; ++hh)
#pragma unroll
                for (int j = 0; j < 4; ++j) {
                    ps0[hh][j] += __shfl_xor(ps0[hh][j], m);
                    pd0[hh][j] += __shfl_xor(pd0[hh][j], m);
                    ps1[hh][j] += __shfl_xor(ps1[hh][j], m);
                    pd1[hh][j] += __shfl_xor(pd1[hh][j], m);
                }
        if (lr == 0) {
#pragma unroll
            for (int j = 0; j < 4; ++j) {
                int row = rowbase + lg * 4 + j;
#pragma unroll
                for (int hh = 0; hh < NH; ++hh) {
                    alsrc[(size_t)row * ALH + hh] = ps0[hh][j];
                    aldst[(size_t)row * ALH + hh] = pd0[hh][j];
                    if (t1) {
                        alsrc[(size_t)(row + 16) * ALH + hh] = ps1[hh][j];
                        aldst[(size_t)(row + 16) * ALH + hh] = pd1[hh][j];
                    }
                }
            }
        }
    }
#pragma unroll
    for (int ct = 0; ct < NCT; ++ct) {
        int col = ct * 16 + lr;
        float bv = BIAS ? bias[col] : 0.f;
#pragma unroll
        for (int j = 0; j < 4; ++j) {
            int row = rowbase + lg * 4 + j;
            out[(size_t)row * OSTR + OOFF + col] = f2bf(acc0[ct][j] + bv);
            if (t1) out[(size_t)(row + 16) * OSTR + OOFF + col] = f2bf(acc1[ct][j] + bv);
        }
    }
}

// ---------------- fused 3-branch aggregation over comb[NN][256] -----------
// lane roles: fl 0-7 GCN, fl 8-15 SAGE, fl 16-31 GAT (head-aligned)
// r8/r10-proven config: int2 pair stream, unroll 4, VGPR 32, Occ ~72%.
// (unroll 8 measured worse twice: r11 91.7us vs 77us, Occ 53%)
template <int H, bool GATBIAS>
__global__ __launch_bounds__(256) void k_aggf(
        const int* __restrict__ rowstart, const int2* __restrict__ pair,
        const float* __restrict__ dis, const float* __restrict__ alsrc,
        const float* __restrict__ aldst, const unsigned short* __restrict__ comb,
        const float* __restrict__ gat_bias,
        unsigned short* __restrict__ outGCN, unsigned short* __restrict__ outGAT,
        unsigned short* __restrict__ outSAGE) {
    int wave = threadIdx.x >> 6, lane = threadIdx.x & 63;
    int n = blockIdx.x * 4 + wave;
    if (n >= NN) return;
    int eg = lane >> 5, fl = lane & 31;
    int f0 = fl * 8;
    bool isGCN = fl < 8, isSAGE = (fl >= 8) && (fl < 16), isGAT = fl >= 16;
    int hh = (H == 2) ? ((fl >= 24) ? 1 : 0) : 0;
    int r0 = rowstart[n], r1 = rowstart[n + 1];
    float dn = dis[n];
    float adn = isGAT ? aldst[n * H + hh] : 0.f;
    float tself = isGAT ? (alsrc[n * H + hh] + adn) : 0.f;
    tself = (tself >= 0.f) ? tself : 0.2f * tself;
    float wsG = __expf(tself);                       // GAT self weight
    float selfw = isGCN ? dn * dn : (isGAT ? wsG : 0.f);
    float acc[8] = {};
    if (eg == 0) {
        u16x8 hv = *(const u16x8*)&comb[(size_t)n * 256 + f0];
#pragma unroll
        for (int j = 0; j < 8; ++j) acc[j] = selfw * bf2f(hv[j]);
    }
    float dsum = 0.f;
#pragma unroll 4
    for (int e = r0 + eg; e < r1; e += 2) {
        int2 p = pair[e];
        int s = p.x;
        float al = isGAT ? alsrc[(size_t)s * H + hh] : 0.f;
        float v = al + adn;
        v = (v >= 0.f) ? v : 0.2f * v;
        float we = __expf(v);
        dsum += we;
        float w = isGCN ? __int_as_float(p.y) * dn : (isGAT ? we : 1.0f);
        u16x8 hs = *(const u16x8*)&comb[(size_t)s * 256 + f0];
#pragma unroll
        for (int jj = 0; jj < 8; ++jj) acc[jj] += w * bf2f(hs[jj]);
    }
    // GAT denominator (masked butterfly within head cluster + cross-eg)
    if (H == 2) {
        dsum += __shfl_xor(dsum, 1);
        dsum += __shfl_xor(dsum, 2);
        dsum += __shfl_xor(dsum, 4);
        dsum += __shfl_xor(dsum, 32);
        dsum *= 0.125f;
    } else {
        dsum += __shfl_xor(dsum, 1);
        dsum += __shfl_xor(dsum, 2);
        dsum += __shfl_xor(dsum, 4);
        dsum += __shfl_xor(dsum, 8);
        dsum += __shfl_xor(dsum, 32);
        dsum *= 0.0625f;
    }
    float dinv = 1.0f / (wsG + dsum + 1e-16f);
    // feature reduce across the two edge-groups
#pragma unroll
    for (int jj = 0; jj < 8; ++jj) acc[jj] += __shfl_xor(acc[jj], 32);
    if (eg == 0) {
        float inv = 1.0f / fmaxf((float)(r1 - r0), 1.0f);
        float mul = isGCN ? 1.0f : (isSAGE ? inv : dinv);
        u16x8 o;
#pragma unroll
        for (int jj = 0; jj < 8; ++jj) {
            float v = acc[jj] * mul;
            if (GATBIAS && isGAT) v += gat_bias[f0 - 128 + jj];
            o[jj] = f2bf(v);
        }
        if (isGCN)       *(u16x8*)&outGCN[(size_t)n * 64 + f0] = o;
        else if (isSAGE) *(u16x8*)&outSAGE[(size_t)n * 64 + (f0 - 64)] = o;
        else             *(u16x8*)&outGAT[(size_t)n * 128 + (f0 - 128)] = o;
    }
}

// ---------------- fused 3-buffer BatchNorm stats ----------------
// octet roles: 0-7 GCN(64), 8-23 GAT(128), 24-31 SAGE(64, +sr if TWO)
template <bool SAGEON, bool TWO>
__global__ void k_bn_stats3(const unsigned short* __restrict__ gcn,
                            const unsigned short* __restrict__ gat,
                            const unsigned short* __restrict__ sage,
                            const unsigned short* __restrict__ sr,
                            float* __restrict__ segG, float* __restrict__ segA,
                            float* __restrict__ segS) {
    __shared__ float lsum[256], lsq[256];
    for (int i = threadIdx.x; i < 256; i += 256) { lsum[i] = 0.f; lsq[i] = 0.f; }
    __syncthreads();
    int oct = threadIdx.x & 31, rl = threadIdx.x >> 5;   // 8 row-lanes
    if (SAGEON || oct < 24) {
        float s[8] = {}, s2[8] = {};
        for (int n = blockIdx.x * 8 + rl; n < NN; n += gridDim.x * 8) {
            u16x8 v;
            if (oct < 8)       v = *(const u16x8*)&gcn[(size_t)n * 64 + oct * 8];
            else if (oct < 24) v = *(const u16x8*)&gat[(size_t)n * 128 + (oct - 8) * 8];
            else               v = *(const u16x8*)&sage[(size_t)n * 64 + (oct - 24) * 8];
            u16x8 w = {};
            if (TWO && oct >= 24) w = *(const u16x8*)&sr[(size_t)n * 64 + (oct - 24) * 8];
#pragma unroll
            for (int j = 0; j < 8; ++j) {
                float f = bf2f(v[j]);
                if (TWO && oct >= 24) f += bf2f(w[j]);
                s[j] += f; s2[j] += f * f;
            }
        }
#pragma unroll
        for (int j = 0; j < 8; ++j) {
            atomicAdd(&lsum[oct * 8 + j], s[j]);
            atomicAdd(&lsq[oct * 8 + j], s2[j]);
        }
    }
    __syncthreads();
    int t = threadIdx.x;
    if (t < 192 || SAGEON) {
        float* base; int f, F;
        if (t < 64)       { base = segG; f = t;       F = 64; }
        else if (t < 192) { base = segA; f = t - 64;  F = 128; }
        else              { base = segS; f = t - 192; F = 64; }
        atomicAdd(&base[f], lsum[t]);
        atomicAdd(&base[F + f], lsq[t]);
    }
}

// ---------------- single-buffer BatchNorm stats (sageM1) -------------------
template <int F, bool TWO>
__global__ void k_bn_stats(const unsigned short* __restrict__ x,
                           const unsigned short* __restrict__ y,
                           float* __restrict__ sums) {
    constexpr int TPR = F / 8;
    constexpr int RPB = 256 / TPR;
    __shared__ float lsum[F], lsq[F];
    for (int i = threadIdx.x; i < F; i += 256) { lsum[i] = 0.f; lsq[i] = 0.f; }
    __syncthreads();
    int fl = threadIdx.x % TPR, rl = threadIdx.x / TPR;
    int f0 = fl * 8;
    float s[8] = {}, s2[8] = {};
    for (int n = blockIdx.x * RPB + rl; n < NN; n += gridDim.x * RPB) {
        u16x8 v = *(const u16x8*)&x[(size_t)n * F + f0];
        u16x8 w = {};
        if (TWO) w = *(const u16x8*)&y[(size_t)n * F + f0];
#pragma unroll
        for (int j = 0; j < 8; ++j) {
            float f = bf2f(v[j]);
            if (TWO) f += bf2f(w[j]);
            s[j] += f; s2[j] += f * f;
        }
    }
#pragma unroll
    for (int off = TPR; off < 64; off <<= 1)
#pragma unroll
        for (int j = 0; j < 8; ++j) { s[j] += __shfl_xor(s[j], off); s2[j] += __shfl_xor(s2[j], off); }
    if ((threadIdx.x & 63) < TPR) {
#pragma unroll
        for (int j = 0; j < 8; ++j) {
            atomicAdd(&lsum[f0 + j], s[j]);
            atomicAdd(&lsq[f0 + j], s2[j]);
        }
    }
    __syncthreads();
    for (int i = threadIdx.x; i < F; i += 256) {
        atomicAdd(&sums[i], lsum[i]);
        atomicAdd(&sums[F + i], lsq[i]);
    }
}

// ---------------- BatchNorm apply, optional dual output --------------------
template <int F, int ACT, bool TWO, bool O1, bool O2, int OOFF>
__global__ void k_bn_apply(const unsigned short* __restrict__ x,
                           const unsigned short* __restrict__ y,
                           const float* __restrict__ sums,
                           const float* __restrict__ gamma, const float* __restrict__ beta,
                           unsigned short* __restrict__ out1, unsigned short* __restrict__ comb) {
    int idx = blockIdx.x * 256 + threadIdx.x;   // units of 8 elems
    if (idx >= NN * F / 8) return;
    int row = idx / (F / 8);
    int f0 = (idx % (F / 8)) * 8;
    u16x8 v = *(const u16x8*)&x[(size_t)idx * 8];
    u16x8 w = {};
    if (TWO) w = *(const u16x8*)&y[(size_t)idx * 8];
    u16x8 o;
#pragma unroll
    for (int j = 0; j < 8; ++j) {
        int f = f0 + j;
        float mean = sums[f] * (1.0f / NN);
        float var = sums[F + f] * (1.0f / NN) - mean * mean;
        float rstd = rsqrtf(var + BN_EPS);
        float raw = bf2f(v[j]);
        if (TWO) raw += bf2f(w[j]);
        float val = (raw - mean) * rstd * gamma[f] + beta[f];
        if (ACT == 1) val = fmaxf(val, 0.f);
        if (ACT == 2) val = (val > 0.f) ? val : (__expf(val) - 1.0f);
        o[j] = f2bf(val);
    }
    if (O1) *(u16x8*)&out1[(size_t)idx * 8] = o;
    if (O2) *(u16x8*)&comb[(size_t)row * 256 + OOFF + f0] = o;
}

// ---------------- pooling (all three branches, one dispatch) ---------------
__global__ void k_pool3(const unsigned short* __restrict__ a,
                        const unsigned short* __restrict__ b,
                        const unsigned short* __restrict__ c,
                        const int* __restrict__ batch, float* __restrict__ pooled) {
    int sel = blockIdx.x / NPB;
    int nb = blockIdx.x % NPB;
    const unsigned short* x = (sel == 0) ? a : ((sel == 1) ? b : c);
    int off = sel * 128;
    int f = threadIdx.x & 127;
    int half = threadIdx.x >> 7;
    int nend = min(NN, (nb + 1) * 128);
    float acc = 0.f; int gcur = -1;
    for (int n = nb * 128 + half; n < nend; n += 2) {
        int g = batch[n];
        if (g != gcur) {
            if (gcur >= 0) atomicAdd(&pooled[(size_t)gcur * 384 + off + f], acc);
            gcur = g; acc = 0.f;
        }
        acc += bf2f(x[(size_t)n * 128 + f]);
    }
    if (gcur >= 0) atomicAdd(&pooled[(size_t)gcur * 384 + off + f], acc);
}

__global__ void k_fusion(const float* __restrict__ pooled, const float* __restrict__ cntG,
                         const float* __restrict__ W, const float* __restrict__ b,
                         float* __restrict__ out) {
    int idx = blockIdx.x * 256 + threadIdx.x;   // NG*128
    if (idx >= NG * 128) return;
    int g = idx / 128, o = idx % 128;
    float inv = 1.0f / fmaxf(cntG[g], 1.0f);
    float acc = b[o];
#pragma unroll 4
    for (int k = 0; k < 384; ++k)
        acc += pooled[g * 384 + k] * inv * W[k * 128 + o];
    out[idx] = acc;
}

// ---------------- launcher ----------------
static inline int grid1(long long n) { return (int)((n + 255) / 256); }

extern "C" void kernel_launch(void* const* d_in, const int* in_sizes, int n_in,
                              void* d_out, int out_size, void* d_ws, size_t ws_size,
                              hipStream_t stream) {
    const float* x       = (const float*)d_in[0];
    const int*   ei      = (const int*)d_in[1];
    const int*   batch   = (const int*)d_in[2];
    const float* gcn_W0  = (const float*)d_in[3];
    const float* gcn_W1  = (const float*)d_in[5];
    const float* gcn_W2  = (const float*)d_in[7];
    const float* gcn_b2  = (const float*)d_in[8];
    const float* gcn_g0  = (const float*)d_in[9];
    const float* gcn_bb0 = (const float*)d_in[10];
    const float* gcn_g1  = (const float*)d_in[11];
    const float* gcn_bb1 = (const float*)d_in[12];
    const float* gat_W0  = (const float*)d_in[13];
    const float* gat_as0 = (const float*)d_in[14];
    const float* gat_ad0 = (const float*)d_in[15];
    const float* gat_W1  = (const float*)d_in[17];
    const float* gat_as1 = (const float*)d_in[18];
    const float* gat_ad1 = (const float*)d_in[19];
    const float* gat_W2  = (const float*)d_in[21];
    const float* gat_as2 = (const float*)d_in[22];
    const float* gat_ad2 = (const float*)d_in[23];
    const float* gat_b2  = (const float*)d_in[24];
    const float* gat_g0  = (const float*)d_in[25];
    const float* gat_bb0 = (const float*)d_in[26];
    const float* gat_g1  = (const float*)d_in[27];
    const float* gat_bb1 = (const float*)d_in[28];
    const float* sage_Wl0 = (const float*)d_in[29];
    const float* sage_Wr0 = (const float*)d_in[30];
    const float* sage_Wl1 = (const float*)d_in[32];
    const float* sage_Wr1 = (const float*)d_in[33];
    const float* sage_Wl2 = (const float*)d_in[35];
    const float* sage_Wr2 = (const float*)d_in[36];
    const float* sage_b2  = (const float*)d_in[37];
    const float* sage_g0  = (const float*)d_in[38];
    const float* sage_bb0 = (const float*)d_in[39];
    const float* sage_g1  = (const float*)d_in[40];
    const float* sage_bb1 = (const float*)d_in[41];
    const float* fus_W    = (const float*)d_in[42];
    const float* fus_b    = (const float*)d_in[43];

    const int* src = ei;
    const int* dst = ei + NE;

    // workspace layout (float units)
    float* ws = (float*)d_ws;
    size_t off = 0;
    auto alloc = [&](size_t n) { float* p = ws + off; off += (n + 3) & ~(size_t)3; return p; };
    unsigned short* combA = (unsigned short*)alloc((size_t)NN * 128);  // NN*256 bf16
    unsigned short* combB = (unsigned short*)alloc((size_t)NN * 128);
    unsigned short* bufGCN  = (unsigned short*)alloc((size_t)NN * 32); // NN*64 bf16
    unsigned short* bufGAT  = (unsigned short*)alloc((size_t)NN * 64); // NN*128 bf16
    unsigned short* bufSAGE = (unsigned short*)alloc((size_t)NN * 32);
    unsigned short* sr0     = (unsigned short*)alloc((size_t)NN * 32);
    unsigned short* sageH0  = (unsigned short*)alloc((size_t)NN * 32);
    unsigned short* sageM1  = (unsigned short*)alloc((size_t)NN * 32);
    unsigned short* wt      = (unsigned short*)alloc(110592 / 2);
    int*   rowstart = (int*)alloc(NN + 1);
    int*   cursor   = (int*)alloc(NN);
    int*   csr_src  = (int*)alloc(NE);
    int2*  pair     = (int2*)alloc((size_t)NE * 2);
    int*   bsum     = (int*)alloc(NB);
    int*   boff     = (int*)alloc(NB);
    float* dis   = alloc(NN);
    float* alsrc = alloc((size_t)NN * 2);
    float* aldst = alloc((size_t)NN * 2);
    // contiguous zero region: bnsum | pooled | cntG | indeg
    float* zr = alloc(6 * 256 + NG * 384 + NG + NN);
    float* bnsum  = zr;
    float* pooled = bnsum + 6 * 256;
    float* cntG   = pooled + NG * 384;
    int*   indeg  = (int*)(cntG + NG);
    (void)ws_size; (void)n_in; (void)in_sizes; (void)out_size;

    unsigned short* sageH1  = sr0;                    // sr0 dead after L0
    unsigned short* finGCN  = combB;                  // combB dead after aggF L1
    unsigned short* finSAGE = combB + (size_t)NN * 128;

    // fused L0 weights [gcn(64)|gat(128)|sWl(64)|sWr(64)] x 128 + per-layer W^T
    unsigned short* wf        = wt;                  // 40960
    unsigned short* gcn_W1t   = wf + 40960;          // 64x64
    unsigned short* gcn_W2t   = gcn_W1t + 4096;      // 64x128
    unsigned short* gat_W1t   = gcn_W2t + 8192;      // 128x128
    unsigned short* gat_W2t   = gat_W1t + 16384;
    unsigned short* sage_Wl1t = gat_W2t + 16384;
    unsigned short* sage_Wr1t = sage_Wl1t + 4096;
    unsigned short* sage_Wl2t = sage_Wr1t + 4096;
    unsigned short* sage_Wr2t = sage_Wl2t + 8192;

    const int gAgg = NN / 4;
    const int gMM  = (NN + 63) / 64;     // k_mm0: 16 rows/wave
    const int gMM2 = (NN + 127) / 128;   // k_mm:  32 rows/wave

    // ---- CSR build + precompute ----
    hipMemsetAsync(zr, 0, (6 * 256 + NG * 384 + NG + NN) * 4, stream);
    k_indeg<<<grid1(NE), 256, 0, stream>>>(dst, indeg);
    k_scan1<<<NB, 256, 0, stream>>>(indeg, rowstart, bsum, dis);
    k_scan2<<<1, 256, 0, stream>>>(bsum, boff);
    k_scan3<<<NB, 256, 0, stream>>>(rowstart, boff, cursor);
    k_fill<<<grid1(NE), 256, 0, stream>>>(src, dst, cursor, csr_src);
    k_pack<<<grid1(NE), 256, 0, stream>>>(csr_src, dis, pair);
    k_count<<<128, 256, 0, stream>>>(batch, cntG);
    WTable wtab = {{
        { gcn_W0, wf, 128, 64 }, { gat_W0, wf + 64 * 128, 128, 128 },
        { sage_Wl0, wf + 192 * 128, 128, 64 }, { sage_Wr0, wf + 256 * 128, 128, 64 },
        { gcn_W1, gcn_W1t, 64, 64 }, { gcn_W2, gcn_W2t, 64, 128 },
        { gat_W1, gat_W1t, 128, 128 }, { gat_W2, gat_W2t, 128, 128 },
        { sage_Wl1, sage_Wl1t, 64, 64 }, { sage_Wr1, sage_Wr1t, 64, 64 },
        { sage_Wl2, sage_Wl2t, 64, 128 }, { sage_Wr2, sage_Wr2t, 64, 128 },
    }};
    k_convw<<<12, 256, 0, stream>>>(wtab);

    // ---- L0: fused matmul -> combA; fused agg -> compacts ----
    k_mm0<<<gMM, 256, 0, stream>>>(x, wf, gat_as0, gat_ad0, alsrc, aldst, combA, sr0);
    k_aggf<2, false><<<gAgg, 256, 0, stream>>>(rowstart, pair, dis, alsrc, aldst,
                                               combA, nullptr, bufGCN, bufGAT, bufSAGE);
    k_bn_stats3<true, true><<<250, 256, 0, stream>>>(
        bufGCN, bufGAT, bufSAGE, sr0, bnsum + 0 * 256, bnsum + 2 * 256, bnsum + 4 * 256);
    // L1 producers -> combB
    k_mm<64, 64, false, false, 1, 0, 256, 0><<<gMM2, 256, 0, stream>>>(
        bufGCN, gcn_W1t, nullptr, nullptr, nullptr,
        bnsum + 0 * 256, gcn_g0, gcn_bb0, nullptr, nullptr, nullptr, nullptr, combB);
    k_mm<128, 128, false, false, 2, 2, 256, 128><<<gMM2, 256, 0, stream>>>(
        bufGAT, gat_W1t, nullptr, nullptr, nullptr,
        bnsum + 2 * 256, gat_g0, gat_bb0, gat_as1, gat_ad1, alsrc, aldst, combB);
    k_bn_apply<64, 1, true, true, true, 64><<<grid1(NN * 8), 256, 0, stream>>>(
        bufSAGE, sr0, bnsum + 4 * 256, sage_g0, sage_bb0, sageH0, combB);

    // ---- L1: fused agg ----
    k_aggf<2, false><<<gAgg, 256, 0, stream>>>(rowstart, pair, dis, alsrc, aldst,
                                               combB, nullptr, bufGCN, bufGAT, bufSAGE);
    k_bn_stats3<false, false><<<250, 256, 0, stream>>>(
        bufGCN, bufGAT, nullptr, nullptr, bnsum + 1 * 256, bnsum + 3 * 256, nullptr);
    k_mm<64, 64, true, false, 0, 0, 64, 0><<<gMM2, 256, 0, stream>>>(
        bufSAGE, sage_Wl1t, sageH0, sage_Wr1t, nullptr,
        nullptr, nullptr, nullptr, nullptr, nullptr, nullptr, nullptr, sageM1);
    // L2 producers -> combA
    k_bn_apply<64, 1, false, false, true, 0><<<grid1(NN * 8), 256, 0, stream>>>(
        bufGCN, nullptr, bnsum + 1 * 256, gcn_g1, gcn_bb1, nullptr, combA);
    k_mm<128, 128, false, false, 2, 1, 256, 128><<<gMM2, 256, 0, stream>>>(
        bufGAT, gat_W2t, nullptr, nullptr, nullptr,
        bnsum + 3 * 256, gat_g1, gat_bb1, gat_as2, gat_ad2, alsrc, aldst, combA);
    k_bn_stats<64, false><<<250, 256, 0, stream>>>(sageM1, nullptr, bnsum + 5 * 256);
    k_bn_apply<64, 1, false, true, true, 64><<<grid1(NN * 8), 256, 0, stream>>>(
        sageM1, nullptr, bnsum + 5 * 256, sage_g1, sage_bb1, sageH1, combA);

    // ---- L2: fused agg (GAT H=1, bias fused) ----
    k_aggf<1, true><<<gAgg, 256, 0, stream>>>(rowstart, pair, dis, alsrc, aldst,
                                              combA, gat_b2, bufGCN, bufGAT, bufSAGE);
    k_mm<64, 128, false, true, 0, 0, 128, 0><<<gMM2, 256, 0, stream>>>(
        bufGCN, gcn_W2t, nullptr, nullptr, gcn_b2,
        nullptr, nullptr, nullptr, nullptr, nullptr, nullptr, nullptr, finGCN);
    k_mm<64, 128, true, true, 0, 0, 128, 0><<<gMM2, 256, 0, stream>>>(
        bufSAGE, sage_Wl2t, sageH1, sage_Wr2t, sage_b2,
        nullptr, nullptr, nullptr, nullptr, nullptr, nullptr, nullptr, finSAGE);

    // ---- pool + fusion ----
    k_pool3<<<3 * NPB, 256, 0, stream>>>(finGCN, bufGAT, finSAGE, batch, pooled);
    k_fusion<<<grid1(NG * 128), 256, 0, stream>>>(pooled, cntG, fus_W, fus_b, (float*)d_out);
}

// Round 13
// 582.860 us; speedup vs baseline: 1.0525x; 1.0159x over previous
//
#include <hip/hip_runtime.h>

#define NN 50000
#define NE 800000
#define NG 50
#define NB 196    // ceil(NN/256)
#define NPB 391   // ceil(NN/128) pool blocks per branch

static constexpr float BN_EPS = 1e-5f;

typedef __attribute__((ext_vector_type(8))) short  bf16x8;
typedef __attribute__((ext_vector_type(8))) unsigned short u16x8;
typedef __attribute__((ext_vector_type(4))) float  f32x4;

// ---------------- bf16 helpers ----------------
__device__ __forceinline__ float bf2f(unsigned short u) {
    return __uint_as_float(((unsigned)u) << 16);
}
__device__ __forceinline__ unsigned short f2bf(float f) {
    unsigned u = __float_as_uint(f);
    unsigned r = (u + 0x7fffu + ((u >> 16) & 1u)) >> 16;   // RNE
    return (unsigned short)r;
}

// ---------------- degree / CSR build ----------------
__global__ void k_indeg(const int* __restrict__ dst, int* __restrict__ indeg) {
    int e = blockIdx.x * 256 + threadIdx.x;
    if (e < NE) atomicAdd(&indeg[dst[e]], 1);
}

// scan + dis + batch-count histogram (k_count folded in)
__global__ void k_scan1(const int* __restrict__ cnt, int* __restrict__ rowstart,
                        int* __restrict__ bsum, float* __restrict__ dis,
                        const int* __restrict__ batch, float* __restrict__ cntG) {
    __shared__ int hist[NG];
    for (int i = threadIdx.x; i < NG; i += 256) hist[i] = 0;
    int i = blockIdx.x * 256 + threadIdx.x;
    int lane = threadIdx.x & 63, wv = threadIdx.x >> 6;
    int v = (i < NN) ? cnt[i] : 0;
    if (i < NN) dis[i] = rsqrtf((float)v + 1.0f);
    int s = v;
#pragma unroll
    for (int d = 1; d < 64; d <<= 1) {
        int t = __shfl_up(s, d);
        if (lane >= d) s += t;
    }
    __shared__ int wtot[4];
    if (lane == 63) wtot[wv] = s;
    __syncthreads();
    if (i < NN) atomicAdd(&hist[batch[i]], 1);
    int woff = 0;
    for (int w = 0; w < wv; ++w) woff += wtot[w];
    if (i < NN) rowstart[i] = woff + s - v;
    if (threadIdx.x == 255) bsum[blockIdx.x] = woff + s;
    __syncthreads();
    for (int g = threadIdx.x; g < NG; g += 256)
        if (hist[g]) atomicAdd(&cntG[g], (float)hist[g]);
}

__global__ void k_scan2(const int* __restrict__ bsum, int* __restrict__ boff) {
    int lane = threadIdx.x & 63, wv = threadIdx.x >> 6;
    int v = (threadIdx.x < NB) ? bsum[threadIdx.x] : 0;
    int s = v;
#pragma unroll
    for (int d = 1; d < 64; d <<= 1) {
        int t = __shfl_up(s, d);
        if (lane >= d) s += t;
    }
    __shared__ int wtot[4];
    if (lane == 63) wtot[wv] = s;
    __syncthreads();
    int woff = 0;
    for (int w = 0; w < wv; ++w) woff += wtot[w];
    if (threadIdx.x < NB) boff[threadIdx.x] = woff + s - v;
}

__global__ void k_scan3(int* __restrict__ rowstart, const int* __restrict__ boff,
                        int* __restrict__ cursor) {
    int i = blockIdx.x * 256 + threadIdx.x;
    if (i < NN) {
        int v = rowstart[i] + boff[blockIdx.x];
        rowstart[i] = v;
        cursor[i] = v;
    }
    if (i == 0) rowstart[NN] = NE;
}

// 4B scatter (cheapest dirty-line form)
__global__ void k_fill(const int* __restrict__ src, const int* __restrict__ dst,
                       int* __restrict__ cursor, int* __restrict__ csr_src) {
    int e = blockIdx.x * 256 + threadIdx.x;
    if (e < NE) {
        int pos = atomicAdd(&cursor[dst[e]], 1);
        csr_src[pos] = src[e];
    }
}

// coalesced pack of {src, dis[src]}
__global__ void k_pack(const int* __restrict__ csr_src, const float* __restrict__ dis,
                       int2* __restrict__ pair) {
    int e = blockIdx.x * 256 + threadIdx.x;
    if (e < NE) {
        int s = csr_src[e];
        pair[e] = make_int2(s, __float_as_int(dis[s]));
    }
}

// ---------------- weight conversion ----------------
struct WDesc { const float* s; unsigned short* d; int fin; int fout; };
struct WTable { WDesc w[12]; };

__global__ void k_convw(WTable t) {
    WDesc wd = t.w[blockIdx.x];
    int total = wd.fin * wd.fout;
    for (int i = threadIdx.x; i < total; i += 256) {
        int c = i / wd.fin, k = i % wd.fin;
        wd.d[i] = f2bf(wd.s[(size_t)k * wd.fout + c]);
    }
}

// ---------------- fused level-0 matmul: x(fp32) @ [gcn0|gat0|sWl0|sWr0] ------
__global__ __launch_bounds__(256) void k_mm0(
        const float* __restrict__ X, const unsigned short* __restrict__ Wf,
        const float* __restrict__ as_, const float* __restrict__ ad_,
        float* __restrict__ alsrc, float* __restrict__ aldst,
        unsigned short* __restrict__ comb, unsigned short* __restrict__ sr0) {
    constexpr int FIN = 128, NCT = 20;   // FOUT = 320
    int wave = threadIdx.x >> 6, lane = threadIdx.x & 63;
    int rowbase = (blockIdx.x * 4 + wave) * 16;
    if (rowbase >= NN) return;
    int lr = lane & 15, lg = lane >> 4;
    int arow = rowbase + lr;
    f32x4 acc[NCT] = {};
    const float* xp = X + (size_t)arow * FIN + lg * 8;
#pragma unroll
    for (int k0 = 0; k0 < FIN; k0 += 32) {
        float4 v0 = *(const float4*)(xp + k0);
        float4 v1 = *(const float4*)(xp + k0 + 4);
        u16x8 au;
        au[0] = f2bf(v0.x); au[1] = f2bf(v0.y); au[2] = f2bf(v0.z); au[3] = f2bf(v0.w);
        au[4] = f2bf(v1.x); au[5] = f2bf(v1.y); au[6] = f2bf(v1.z); au[7] = f2bf(v1.w);
        bf16x8 a1 = *(bf16x8*)&au;
#pragma unroll
        for (int ct = 0; ct < NCT; ++ct) {
            int wcol = ct * 16 + lr;
            bf16x8 b1 = *(const bf16x8*)(Wf + (size_t)wcol * FIN + k0 + lg * 8);
            acc[ct] = __builtin_amdgcn_mfma_f32_16x16x32_bf16(a1, b1, acc[ct], 0, 0, 0);
        }
    }
    // GAT attention-logit epilogue on fused cols 64..191
    {
        float ps[2][4] = {}, pd[2][4] = {};
#pragma unroll
        for (int ct = 4; ct < 12; ++ct) {
            int hh = (ct >= 8) ? 1 : 0;
            int colg = ct * 16 + lr - 64;
            float cs = as_[colg], cd = ad_[colg];
#pragma unroll
            for (int j = 0; j < 4; ++j) {
                ps[hh][j] += acc[ct][j] * cs;
                pd[hh][j] += acc[ct][j] * cd;
            }
        }
#pragma unroll
        for (int m = 1; m < 16; m <<= 1)
#pragma unroll
            for (int hh = 0; hh < 2; ++hh)
#pragma unroll
                for (int j = 0; j < 4; ++j) {
                    ps[hh][j] += __shfl_xor(ps[hh][j], m);
                    pd[hh][j] += __shfl_xor(pd[hh][j], m);
                }
        if (lr == 0) {
#pragma unroll
            for (int j = 0; j < 4; ++j) {
                int row = rowbase + lg * 4 + j;
#pragma unroll
                for (int hh = 0; hh < 2; ++hh) {
                    alsrc[(size_t)row * 2 + hh] = ps[hh][j];
                    aldst[(size_t)row * 2 + hh] = pd[hh][j];
                }
            }
        }
    }
#pragma unroll
    for (int ct = 0; ct < NCT; ++ct) {
        int col = ct * 16 + lr;
#pragma unroll
        for (int j = 0; j < 4; ++j) {
            int row = rowbase + lg * 4 + j;
            unsigned short v = f2bf(acc[ct][j]);
            if (ct < 4)       comb[(size_t)row * 256 + col] = v;              // GCN
            else if (ct < 12) comb[(size_t)row * 256 + 128 + (col - 64)] = v; // GAT
            else if (ct < 16) comb[(size_t)row * 256 + 64 + (col - 192)] = v; // SAGE-L
            else              sr0[(size_t)row * 64 + (col - 256)] = v;
        }
    }
}

// ---------------- MFMA matmul, 32 rows/wave, fused BN+act on A1 ------------
template <int FIN, int FOUT, bool DUAL, bool BIAS, int BNACT, int ALH, int OSTR, int OOFF>
__global__ __launch_bounds__(256) void k_mm(
        const unsigned short* __restrict__ A1, const unsigned short* __restrict__ W1t,
        const unsigned short* __restrict__ A2, const unsigned short* __restrict__ W2t,
        const float* __restrict__ bias,
        const float* __restrict__ bns, const float* __restrict__ bng, const float* __restrict__ bnb,
        const float* __restrict__ as_, const float* __restrict__ ad_,
        float* __restrict__ alsrc, float* __restrict__ aldst,
        unsigned short* __restrict__ out) {
    constexpr int NCT = FOUT / 16;
    int wave = threadIdx.x >> 6, lane = threadIdx.x & 63;
    int rowbase = (blockIdx.x * 4 + wave) * 32;
    if (rowbase >= NN) return;
    bool t1 = (rowbase + 16) < NN;          // NN%32==16 -> last wave tile0 only
    int lr = lane & 15, lg = lane >> 4;
    int arow0 = rowbase + lr;
    int arow1 = t1 ? (arow0 + 16) : arow0;
    f32x4 acc0[NCT] = {}, acc1[NCT] = {};
    const unsigned short* a1p0 = A1 + (size_t)arow0 * FIN + lg * 8;
    const unsigned short* a1p1 = A1 + (size_t)arow1 * FIN + lg * 8;
    const unsigned short* a2p0 = DUAL ? (A2 + (size_t)arow0 * FIN + lg * 8) : nullptr;
    const unsigned short* a2p1 = DUAL ? (A2 + (size_t)arow1 * FIN + lg * 8) : nullptr;
#pragma unroll
    for (int k0 = 0; k0 < FIN; k0 += 32) {
        bf16x8 a0, a1v;
        if (BNACT == 0) {
            a0  = *(const bf16x8*)(a1p0 + k0);
            a1v = *(const bf16x8*)(a1p1 + k0);
        } else {
            u16x8 r0v = *(const u16x8*)(a1p0 + k0);
            u16x8 r1v = *(const u16x8*)(a1p1 + k0);
            u16x8 t0, t1v;
#pragma unroll
            for (int j = 0; j < 8; ++j) {
                int f = k0 + lg * 8 + j;
                float mean = bns[f] * (1.0f / NN);
                float var = bns[FIN + f] * (1.0f / NN) - mean * mean;
                float rstd = rsqrtf(var + BN_EPS);
                float g = bng[f], bb = bnb[f];
                float v0 = (bf2f(r0v[j]) - mean) * rstd * g + bb;
                float v1 = (bf2f(r1v[j]) - mean) * rstd * g + bb;
                if (BNACT == 1) { v0 = fmaxf(v0, 0.f); v1 = fmaxf(v1, 0.f); }
                if (BNACT == 2) {
                    v0 = (v0 > 0.f) ? v0 : (__expf(v0) - 1.0f);
                    v1 = (v1 > 0.f) ? v1 : (__expf(v1) - 1.0f);
                }
                t0[j] = f2bf(v0); t1v[j] = f2bf(v1);
            }
            a0 = *(bf16x8*)&t0; a1v = *(bf16x8*)&t1v;
        }
        bf16x8 a20 = {}, a21 = {};
        if (DUAL) { a20 = *(const bf16x8*)(a2p0 + k0); a21 = *(const bf16x8*)(a2p1 + k0); }
#pragma unroll
        for (int ct = 0; ct < NCT; ++ct) {
            int wcol = ct * 16 + lr;
            bf16x8 b1 = *(const bf16x8*)(W1t + (size_t)wcol * FIN + k0 + lg * 8);
            acc0[ct] = __builtin_amdgcn_mfma_f32_16x16x32_bf16(a0, b1, acc0[ct], 0, 0, 0);
            acc1[ct] = __builtin_amdgcn_mfma_f32_16x16x32_bf16(a1v, b1, acc1[ct], 0, 0, 0);
            if (DUAL) {
                bf16x8 b2 = *(const bf16x8*)(W2t + (size_t)wcol * FIN + k0 + lg * 8);
                acc0[ct] = __builtin_amdgcn_mfma_f32_16x16x32_bf16(a20, b2, acc0[ct], 0, 0, 0);
                acc1[ct] = __builtin_amdgcn_mfma_f32_16x16x32_bf16(a21, b2, acc1[ct], 0, 0, 0);
            }
        }
    }
    if (ALH > 0) {
        constexpr int NH = (ALH > 0) ? ALH : 1;
        float ps0[NH][4] = {}, pd0[NH][4] = {}, ps1[NH][4] = {}, pd1[NH][4] = {};
#pragma unroll
        for (int ct = 0; ct < NCT; ++ct) {
            int hh = (ALH == 2 && ct >= NCT / 2) ? 1 : 0;
            int col = ct * 16 + lr;
            float cs = as_[col], cd = ad_[col];
#pragma unroll
            for (int j = 0; j < 4; ++j) {
                ps0[hh][j] += acc0[ct][j] * cs;
                pd0[hh][j] += acc0[ct][j] * cd;
                ps1[hh][j] += acc1[ct][j] * cs;
                pd1[hh][j] += acc1[ct][j] * cd;
            }
        }
#pragma unroll
        for (int m = 1; m < 16; m <<= 1)
#pragma unroll
            for (int hh = 0; hh < NH; ++hh)
#pragma unroll
                for (int j = 0; j < 4; ++j) {
                    ps0[hh][j] += __shfl_xor(ps0[hh][j], m);
                    pd0[hh][j] += __shfl_xor(pd0[hh][j], m);
                    ps1[hh][j] += __shfl_xor(ps1[hh][j], m);
                    pd1[hh][j] += __shfl_xor(pd1[hh][j], m);
                }
        if (lr == 0) {
#pragma unroll
            for (int j = 0; j < 4; ++j) {
                int row = rowbase + lg * 4 + j;
#pragma unroll
                for (int hh = 0; hh < NH; ++hh) {
                    alsrc[(size_t)row * ALH + hh] = ps0[hh][j];
                    aldst[(size_t)row * ALH + hh] = pd0[hh][j];
                    if (t1) {
                        alsrc[(size_t)(row + 16) * ALH + hh] = ps1[hh][j];
                        aldst[(size_t)(row + 16) * ALH + hh] = pd1[hh][j];
                    }
                }
            }
        }
    }
#pragma unroll
    for (int ct = 0; ct < NCT; ++ct) {
        int col = ct * 16 + lr;
        float bv = BIAS ? bias[col] : 0.f;
#pragma unroll
        for (int j = 0; j < 4; ++j) {
            int row = rowbase + lg * 4 + j;
            out[(size_t)row * OSTR + OOFF + col] = f2bf(acc0[ct][j] + bv);
            if (t1) out[(size_t)(row + 16) * OSTR + OOFF + col] = f2bf(acc1[ct][j] + bv);
        }
    }
}

// ---------------- fused 3-branch aggregation over comb[NN][256] -----------
// r12 config (unroll 4, VGPR 32) + software-pipelined pair prefetch:
// next iteration's pair is loaded (clamped, branchless) before this
// iteration's gather, breaking the pair->gather serial chain.
template <int H, bool GATBIAS>
__global__ __launch_bounds__(256) void k_aggf(
        const int* __restrict__ rowstart, const int2* __restrict__ pair,
        const float* __restrict__ dis, const float* __restrict__ alsrc,
        const float* __restrict__ aldst, const unsigned short* __restrict__ comb,
        const float* __restrict__ gat_bias,
        unsigned short* __restrict__ outGCN, unsigned short* __restrict__ outGAT,
        unsigned short* __restrict__ outSAGE) {
    int wave = threadIdx.x >> 6, lane = threadIdx.x & 63;
    int n = blockIdx.x * 4 + wave;
    if (n >= NN) return;
    int eg = lane >> 5, fl = lane & 31;
    int f0 = fl * 8;
    bool isGCN = fl < 8, isSAGE = (fl >= 8) && (fl < 16), isGAT = fl >= 16;
    int hh = (H == 2) ? ((fl >= 24) ? 1 : 0) : 0;
    int r0 = rowstart[n], r1 = rowstart[n + 1];
    float dn = dis[n];
    float adn = isGAT ? aldst[n * H + hh] : 0.f;
    float tself = isGAT ? (alsrc[n * H + hh] + adn) : 0.f;
    tself = (tself >= 0.f) ? tself : 0.2f * tself;
    float wsG = __expf(tself);                       // GAT self weight
    float selfw = isGCN ? dn * dn : (isGAT ? wsG : 0.f);
    float acc[8] = {};
    if (eg == 0) {
        u16x8 hv = *(const u16x8*)&comb[(size_t)n * 256 + f0];
#pragma unroll
        for (int j = 0; j < 8; ++j) acc[j] = selfw * bf2f(hv[j]);
    }
    float dsum = 0.f;
    int e = r0 + eg;
    int2 p = (e < r1) ? pair[e] : make_int2(0, 0);
#pragma unroll 4
    for (; e < r1; e += 2) {
        int en = min(e + 2, r1 - 1);           // clamped prefetch (branchless)
        int2 pn = pair[en];
        int s = p.x;
        float al = isGAT ? alsrc[(size_t)s * H + hh] : 0.f;
        float v = al + adn;
        v = (v >= 0.f) ? v : 0.2f * v;
        float we = __expf(v);
        dsum += we;
        float w = isGCN ? __int_as_float(p.y) * dn : (isGAT ? we : 1.0f);
        u16x8 hs = *(const u16x8*)&comb[(size_t)s * 256 + f0];
#pragma unroll
        for (int jj = 0; jj < 8; ++jj) acc[jj] += w * bf2f(hs[jj]);
        p = pn;
    }
    // GAT denominator (masked butterfly within head cluster + cross-eg)
    if (H == 2) {
        dsum += __shfl_xor(dsum, 1);
        dsum += __shfl_xor(dsum, 2);
        dsum += __shfl_xor(dsum, 4);
        dsum += __shfl_xor(dsum, 32);
        dsum *= 0.125f;
    } else {
        dsum += __shfl_xor(dsum, 1);
        dsum += __shfl_xor(dsum, 2);
        dsum += __shfl_xor(dsum, 4);
        dsum += __shfl_xor(dsum, 8);
        dsum += __shfl_xor(dsum, 32);
        dsum *= 0.0625f;
    }
    float dinv = 1.0f / (wsG + dsum + 1e-16f);
    // feature reduce across the two edge-groups
#pragma unroll
    for (int jj = 0; jj < 8; ++jj) acc[jj] += __shfl_xor(acc[jj], 32);
    if (eg == 0) {
        float inv = 1.0f / fmaxf((float)(r1 - r0), 1.0f);
        float mul = isGCN ? 1.0f : (isSAGE ? inv : dinv);
        u16x8 o;
#pragma unroll
        for (int jj = 0; jj < 8; ++jj) {
            float v = acc[jj] * mul;
            if (GATBIAS && isGAT) v += gat_bias[f0 - 128 + jj];
            o[jj] = f2bf(v);
        }
        if (isGCN)       *(u16x8*)&outGCN[(size_t)n * 64 + f0] = o;
        else if (isSAGE) *(u16x8*)&outSAGE[(size_t)n * 64 + (f0 - 64)] = o;
        else             *(u16x8*)&outGAT[(size_t)n * 128 + (f0 - 128)] = o;
    }
}

// ---------------- fused 3-buffer BatchNorm stats ----------------
template <bool SAGEON, bool TWO>
__global__ void k_bn_stats3(const unsigned short* __restrict__ gcn,
                            const unsigned short* __restrict__ gat,
                            const unsigned short* __restrict__ sage,
                            const unsigned short* __restrict__ sr,
                            float* __restrict__ segG, float* __restrict__ segA,
                            float* __restrict__ segS) {
    __shared__ float lsum[256], lsq[256];
    for (int i = threadIdx.x; i < 256; i += 256) { lsum[i] = 0.f; lsq[i] = 0.f; }
    __syncthreads();
    int oct = threadIdx.x & 31, rl = threadIdx.x >> 5;   // 8 row-lanes
    if (SAGEON || oct < 24) {
        float s[8] = {}, s2[8] = {};
        for (int n = blockIdx.x * 8 + rl; n < NN; n += gridDim.x * 8) {
            u16x8 v;
            if (oct < 8)       v = *(const u16x8*)&gcn[(size_t)n * 64 + oct * 8];
            else if (oct < 24) v = *(const u16x8*)&gat[(size_t)n * 128 + (oct - 8) * 8];
            else               v = *(const u16x8*)&sage[(size_t)n * 64 + (oct - 24) * 8];
            u16x8 w = {};
            if (TWO && oct >= 24) w = *(const u16x8*)&sr[(size_t)n * 64 + (oct - 24) * 8];
#pragma unroll
            for (int j = 0; j < 8; ++j) {
                float f = bf2f(v[j]);
                if (TWO && oct >= 24) f += bf2f(w[j]);
                s[j] += f; s2[j] += f * f;
            }
        }
#pragma unroll
        for (int j = 0; j < 8; ++j) {
            atomicAdd(&lsum[oct * 8 + j], s[j]);
            atomicAdd(&lsq[oct * 8 + j], s2[j]);
        }
    }
    __syncthreads();
    int t = threadIdx.x;
    if (t < 192 || SAGEON) {
        float* base; int f, F;
        if (t < 64)       { base = segG; f = t;       F = 64; }
        else if (t < 192) { base = segA; f = t - 64;  F = 128; }
        else              { base = segS; f = t - 192; F = 64; }
        atomicAdd(&base[f], lsum[t]);
        atomicAdd(&base[F + f], lsq[t]);
    }
}

// ---------------- single-buffer BatchNorm stats (sageM1) -------------------
template <int F, bool TWO>
__global__ void k_bn_stats(const unsigned short* __restrict__ x,
                           const unsigned short* __restrict__ y,
                           float* __restrict__ sums) {
    constexpr int TPR = F / 8;
    constexpr int RPB = 256 / TPR;
    __shared__ float lsum[F], lsq[F];
    for (int i = threadIdx.x; i < F; i += 256) { lsum[i] = 0.f; lsq[i] = 0.f; }
    __syncthreads();
    int fl = threadIdx.x % TPR, rl = threadIdx.x / TPR;
    int f0 = fl * 8;
    float s[8] = {}, s2[8] = {};
    for (int n = blockIdx.x * RPB + rl; n < NN; n += gridDim.x * RPB) {
        u16x8 v = *(const u16x8*)&x[(size_t)n * F + f0];
        u16x8 w = {};
        if (TWO) w = *(const u16x8*)&y[(size_t)n * F + f0];
#pragma unroll
        for (int j = 0; j < 8; ++j) {
            float f = bf2f(v[j]);
            if (TWO) f += bf2f(w[j]);
            s[j] += f; s2[j] += f * f;
        }
    }
#pragma unroll
    for (int off = TPR; off < 64; off <<= 1)
#pragma unroll
        for (int j = 0; j < 8; ++j) { s[j] += __shfl_xor(s[j], off); s2[j] += __shfl_xor(s2[j], off); }
    if ((threadIdx.x & 63) < TPR) {
#pragma unroll
        for (int j = 0; j < 8; ++j) {
            atomicAdd(&lsum[f0 + j], s[j]);
            atomicAdd(&lsq[f0 + j], s2[j]);
        }
    }
    __syncthreads();
    for (int i = threadIdx.x; i < F; i += 256) {
        atomicAdd(&sums[i], lsum[i]);
        atomicAdd(&sums[F + i], lsq[i]);
    }
}

// ---------------- BatchNorm apply, optional dual output --------------------
template <int F, int ACT, bool TWO, bool O1, bool O2, int OOFF>
__global__ void k_bn_apply(const unsigned short* __restrict__ x,
                           const unsigned short* __restrict__ y,
                           const float* __restrict__ sums,
                           const float* __restrict__ gamma, const float* __restrict__ beta,
                           unsigned short* __restrict__ out1, unsigned short* __restrict__ comb) {
    int idx = blockIdx.x * 256 + threadIdx.x;   // units of 8 elems
    if (idx >= NN * F / 8) return;
    int row = idx / (F / 8);
    int f0 = (idx % (F / 8)) * 8;
    u16x8 v = *(const u16x8*)&x[(size_t)idx * 8];
    u16x8 w = {};
    if (TWO) w = *(const u16x8*)&y[(size_t)idx * 8];
    u16x8 o;
#pragma unroll
    for (int j = 0; j < 8; ++j) {
        int f = f0 + j;
        float mean = sums[f] * (1.0f / NN);
        float var = sums[F + f] * (1.0f / NN) - mean * mean;
        float rstd = rsqrtf(var + BN_EPS);
        float raw = bf2f(v[j]);
        if (TWO) raw += bf2f(w[j]);
        float val = (raw - mean) * rstd * gamma[f] + beta[f];
        if (ACT == 1) val = fmaxf(val, 0.f);
        if (ACT == 2) val = (val > 0.f) ? val : (__expf(val) - 1.0f);
        o[j] = f2bf(val);
    }
    if (O1) *(u16x8*)&out1[(size_t)idx * 8] = o;
    if (O2) *(u16x8*)&comb[(size_t)row * 256 + OOFF + f0] = o;
}

// ---------------- pooling (all three branches, one dispatch) ---------------
__global__ void k_pool3(const unsigned short* __restrict__ a,
                        const unsigned short* __restrict__ b,
                        const unsigned short* __restrict__ c,
                        const int* __restrict__ batch, float* __restrict__ pooled) {
    int sel = blockIdx.x / NPB;
    int nb = blockIdx.x % NPB;
    const unsigned short* x = (sel == 0) ? a : ((sel == 1) ? b : c);
    int off = sel * 128;
    int f = threadIdx.x & 127;
    int half = threadIdx.x >> 7;
    int nend = min(NN, (nb + 1) * 128);
    float acc = 0.f; int gcur = -1;
    for (int n = nb * 128 + half; n < nend; n += 2) {
        int g = batch[n];
        if (g != gcur) {
            if (gcur >= 0) atomicAdd(&pooled[(size_t)gcur * 384 + off + f], acc);
            gcur = g; acc = 0.f;
        }
        acc += bf2f(x[(size_t)n * 128 + f]);
    }
    if (gcur >= 0) atomicAdd(&pooled[(size_t)gcur * 384 + off + f], acc);
}

__global__ void k_fusion(const float* __restrict__ pooled, const float* __restrict__ cntG,
                         const float* __restrict__ W, const float* __restrict__ b,
                         float* __restrict__ out) {
    int idx = blockIdx.x * 256 + threadIdx.x;   // NG*128
    if (idx >= NG * 128) return;
    int g = idx / 128, o = idx % 128;
    float inv = 1.0f / fmaxf(cntG[g], 1.0f);
    float acc = b[o];
#pragma unroll 4
    for (int k = 0; k < 384; ++k)
        acc += pooled[g * 384 + k] * inv * W[k * 128 + o];
    out[idx] = acc;
}

// ---------------- launcher ----------------
static inline int grid1(long long n) { return (int)((n + 255) / 256); }

extern "C" void kernel_launch(void* const* d_in, const int* in_sizes, int n_in,
                              void* d_out, int out_size, void* d_ws, size_t ws_size,
                              hipStream_t stream) {
    const float* x       = (const float*)d_in[0];
    const int*   ei      = (const int*)d_in[1];
    const int*   batch   = (const int*)d_in[2];
    const float* gcn_W0  = (const float*)d_in[3];
    const float* gcn_W1  = (const float*)d_in[5];
    const float* gcn_W2  = (const float*)d_in[7];
    const float* gcn_b2  = (const float*)d_in[8];
    const float* gcn_g0  = (const float*)d_in[9];
    const float* gcn_bb0 = (const float*)d_in[10];
    const float* gcn_g1  = (const float*)d_in[11];
    const float* gcn_bb1 = (const float*)d_in[12];
    const float* gat_W0  = (const float*)d_in[13];
    const float* gat_as0 = (const float*)d_in[14];
    const float* gat_ad0 = (const float*)d_in[15];
    const float* gat_W1  = (const float*)d_in[17];
    const float* gat_as1 = (const float*)d_in[18];
    const float* gat_ad1 = (const float*)d_in[19];
    const float* gat_W2  = (const float*)d_in[21];
    const float* gat_as2 = (const float*)d_in[22];
    const float* gat_ad2 = (const float*)d_in[23];
    const float* gat_b2  = (const float*)d_in[24];
    const float* gat_g0  = (const float*)d_in[25];
    const float* gat_bb0 = (const float*)d_in[26];
    const float* gat_g1  = (const float*)d_in[27];
    const float* gat_bb1 = (const float*)d_in[28];
    const float* sage_Wl0 = (const float*)d_in[29];
    const float* sage_Wr0 = (const float*)d_in[30];
    const float* sage_Wl1 = (const float*)d_in[32];
    const float* sage_Wr1 = (const float*)d_in[33];
    const float* sage_Wl2 = (const float*)d_in[35];
    const float* sage_Wr2 = (const float*)d_in[36];
    const float* sage_b2  = (const float*)d_in[37];
    const float* sage_g0  = (const float*)d_in[38];
    const float* sage_bb0 = (const float*)d_in[39];
    const float* sage_g1  = (const float*)d_in[40];
    const float* sage_bb1 = (const float*)d_in[41];
    const float* fus_W    = (const float*)d_in[42];
    const float* fus_b    = (const float*)d_in[43];

    const int* src = ei;
    const int* dst = ei + NE;

    // workspace layout (float units)
    float* ws = (float*)d_ws;
    size_t off = 0;
    auto alloc = [&](size_t n) { float* p = ws + off; off += (n + 3) & ~(size_t)3; return p; };
    unsigned short* combA = (unsigned short*)alloc((size_t)NN * 128);  // NN*256 bf16
    unsigned short* combB = (unsigned short*)alloc((size_t)NN * 128);
    unsigned short* bufGCN  = (unsigned short*)alloc((size_t)NN * 32); // NN*64 bf16
    unsigned short* bufGAT  = (unsigned short*)alloc((size_t)NN * 64); // NN*128 bf16
    unsigned short* bufSAGE = (unsigned short*)alloc((size_t)NN * 32);
    unsigned short* sr0     = (unsigned short*)alloc((size_t)NN * 32);
    unsigned short* sageH0  = (unsigned short*)alloc((size_t)NN * 32);
    unsigned short* sageM1  = (unsigned short*)alloc((size_t)NN * 32);
    unsigned short* wt      = (unsigned short*)alloc(110592 / 2);
    int*   rowstart = (int*)alloc(NN + 1);
    int*   cursor   = (int*)alloc(NN);
    int*   csr_src  = (int*)alloc(NE);
    int2*  pair     = (int2*)alloc((size_t)NE * 2);
    int*   bsum     = (int*)alloc(NB);
    int*   boff     = (int*)alloc(NB);
    float* dis   = alloc(NN);
    float* alsrc = alloc((size_t)NN * 2);
    float* aldst = alloc((size_t)NN * 2);
    // contiguous zero region: bnsum | pooled | cntG | indeg
    float* zr = alloc(6 * 256 + NG * 384 + NG + NN);
    float* bnsum  = zr;
    float* pooled = bnsum + 6 * 256;
    float* cntG   = pooled + NG * 384;
    int*   indeg  = (int*)(cntG + NG);
    (void)ws_size; (void)n_in; (void)in_sizes; (void)out_size;

    unsigned short* sageH1  = sr0;                    // sr0 dead after L0
    unsigned short* finGCN  = combB;                  // combB dead after aggF L1
    unsigned short* finSAGE = combB + (size_t)NN * 128;

    // fused L0 weights [gcn(64)|gat(128)|sWl(64)|sWr(64)] x 128 + per-layer W^T
    unsigned short* wf        = wt;                  // 40960
    unsigned short* gcn_W1t   = wf + 40960;          // 64x64
    unsigned short* gcn_W2t   = gcn_W1t + 4096;      // 64x128
    unsigned short* gat_W1t   = gcn_W2t + 8192;      // 128x128
    unsigned short* gat_W2t   = gat_W1t + 16384;
    unsigned short* sage_Wl1t = gat_W2t + 16384;
    unsigned short* sage_Wr1t = sage_Wl1t + 4096;
    unsigned short* sage_Wl2t = sage_Wr1t + 4096;
    unsigned short* sage_Wr2t = sage_Wl2t + 8192;

    const int gAgg = NN / 4;
    const int gMM  = (NN + 63) / 64;     // k_mm0: 16 rows/wave
    const int gMM2 = (NN + 127) / 128;   // k_mm:  32 rows/wave

    // ---- CSR build + precompute ----
    hipMemsetAsync(zr, 0, (6 * 256 + NG * 384 + NG + NN) * 4, stream);
    k_indeg<<<grid1(NE), 256, 0, stream>>>(dst, indeg);
    k_scan1<<<NB, 256, 0, stream>>>(indeg, rowstart, bsum, dis, batch, cntG);
    k_scan2<<<1, 256, 0, stream>>>(bsum, boff);
    k_scan3<<<NB, 256, 0, stream>>>(rowstart, boff, cursor);
    k_fill<<<grid1(NE), 256, 0, stream>>>(src, dst, cursor, csr_src);
    k_pack<<<grid1(NE), 256, 0, stream>>>(csr_src, dis, pair);
    WTable wtab = {{
        { gcn_W0, wf, 128, 64 }, { gat_W0, wf + 64 * 128, 128, 128 },
        { sage_Wl0, wf + 192 * 128, 128, 64 }, { sage_Wr0, wf + 256 * 128, 128, 64 },
        { gcn_W1, gcn_W1t, 64, 64 }, { gcn_W2, gcn_W2t, 64, 128 },
        { gat_W1, gat_W1t, 128, 128 }, { gat_W2, gat_W2t, 128, 128 },
        { sage_Wl1, sage_Wl1t, 64, 64 }, { sage_Wr1, sage_Wr1t, 64, 64 },
        { sage_Wl2, sage_Wl2t, 64, 128 }, { sage_Wr2, sage_Wr2t, 64, 128 },
    }};
    k_convw<<<12, 256, 0, stream>>>(wtab);

    // ---- L0: fused matmul -> combA; fused agg -> compacts ----
    k_mm0<<<gMM, 256, 0, stream>>>(x, wf, gat_as0, gat_ad0, alsrc, aldst, combA, sr0);
    k_aggf<2, false><<<gAgg, 256, 0, stream>>>(rowstart, pair, dis, alsrc, aldst,
                                               combA, nullptr, bufGCN, bufGAT, bufSAGE);
    k_bn_stats3<true, true><<<250, 256, 0, stream>>>(
        bufGCN, bufGAT, bufSAGE, sr0, bnsum + 0 * 256, bnsum + 2 * 256, bnsum + 4 * 256);
    // L1 producers -> combB
    k_mm<64, 64, false, false, 1, 0, 256, 0><<<gMM2, 256, 0, stream>>>(
        bufGCN, gcn_W1t, nullptr, nullptr, nullptr,
        bnsum + 0 * 256, gcn_g0, gcn_bb0, nullptr, nullptr, nullptr, nullptr, combB);
    k_mm<128, 128, false, false, 2, 2, 256, 128><<<gMM2, 256, 0, stream>>>(
        bufGAT, gat_W1t, nullptr, nullptr, nullptr,
        bnsum + 2 * 256, gat_g0, gat_bb0, gat_as1, gat_ad1, alsrc, aldst, combB);
    k_bn_apply<64, 1, true, true, true, 64><<<grid1(NN * 8), 256, 0, stream>>>(
        bufSAGE, sr0, bnsum + 4 * 256, sage_g0, sage_bb0, sageH0, combB);

    // ---- L1: fused agg ----
    k_aggf<2, false><<<gAgg, 256, 0, stream>>>(rowstart, pair, dis, alsrc, aldst,
                                               combB, nullptr, bufGCN, bufGAT, bufSAGE);
    k_bn_stats3<false, false><<<250, 256, 0, stream>>>(
        bufGCN, bufGAT, nullptr, nullptr, bnsum + 1 * 256, bnsum + 3 * 256, nullptr);
    k_mm<64, 64, true, false, 0, 0, 64, 0><<<gMM2, 256, 0, stream>>>(
        bufSAGE, sage_Wl1t, sageH0, sage_Wr1t, nullptr,
        nullptr, nullptr, nullptr, nullptr, nullptr, nullptr, nullptr, sageM1);
    // L2 producers -> combA
    k_bn_apply<64, 1, false, false, true, 0><<<grid1(NN * 8), 256, 0, stream>>>(
        bufGCN, nullptr, bnsum + 1 * 256, gcn_g1, gcn_bb1, nullptr, combA);
    k_mm<128, 128, false, false, 2, 1, 256, 128><<<gMM2, 256, 0, stream>>>(
        bufGAT, gat_W2t, nullptr, nullptr, nullptr,
        bnsum + 3 * 256, gat_g1, gat_bb1, gat_as2, gat_ad2, alsrc, aldst, combA);
    k_bn_stats<64, false><<<250, 256, 0, stream>>>(sageM1, nullptr, bnsum + 5 * 256);
    k_bn_apply<64, 1, false, true, true, 64><<<grid1(NN * 8), 256, 0, stream>>>(
        sageM1, nullptr, bnsum + 5 * 256, sage_g1, sage_bb1, sageH1, combA);

    // ---- L2: fused agg (GAT H=1, bias fused) ----
    k_aggf<1, true><<<gAgg, 256, 0, stream>>>(rowstart, pair, dis, alsrc, aldst,
                                              combA, gat_b2, bufGCN, bufGAT, bufSAGE);
    k_mm<64, 128, false, true, 0, 0, 128, 0><<<gMM2, 256, 0, stream>>>(
        bufGCN, gcn_W2t, nullptr, nullptr, gcn_b2,
        nullptr, nullptr, nullptr, nullptr, nullptr, nullptr, nullptr, finGCN);
    k_mm<64, 128, true, true, 0, 0, 128, 0><<<gMM2, 256, 0, stream>>>(
        bufSAGE, sage_Wl2t, sageH1, sage_Wr2t, sage_b2,
        nullptr, nullptr, nullptr, nullptr, nullptr, nullptr, nullptr, finSAGE);

    // ---- pool + fusion ----
    k_pool3<<<3 * NPB, 256, 0, stream>>>(finGCN, bufGAT, finSAGE, batch, pooled);
    k_fusion<<<grid1(NG * 128), 256, 0, stream>>>(pooled, cntG, fus_W, fus_b, (float*)d_out);
}

// Round 14
// 582.079 us; speedup vs baseline: 1.0539x; 1.0013x over previous
//
#include <hip/hip_runtime.h>

#define NN 50000
#define NE 800000
#define NG 50
#define NB 196    // ceil(NN/256)
#define NPB 391   // ceil(NN/128) pool blocks per branch

static constexpr float BN_EPS = 1e-5f;

typedef __attribute__((ext_vector_type(8))) short  bf16x8;
typedef __attribute__((ext_vector_type(8))) unsigned short u16x8;
typedef __attribute__((ext_vector_type(4))) float  f32x4;

// ---------------- bf16 helpers ----------------
__device__ __forceinline__ float bf2f(unsigned short u) {
    return __uint_as_float(((unsigned)u) << 16);
}
__device__ __forceinline__ unsigned short f2bf(float f) {
    unsigned u = __float_as_uint(f);
    unsigned r = (u + 0x7fffu + ((u >> 16) & 1u)) >> 16;   // RNE
    return (unsigned short)r;
}

// ---------------- degree / CSR build ----------------
__global__ void k_indeg(const int* __restrict__ dst, int* __restrict__ indeg) {
    int e = blockIdx.x * 256 + threadIdx.x;
    if (e < NE) atomicAdd(&indeg[dst[e]], 1);
}

// scan + dis + batch-count histogram (k_count folded in)
__global__ void k_scan1(const int* __restrict__ cnt, int* __restrict__ rowstart,
                        int* __restrict__ bsum, float* __restrict__ dis,
                        const int* __restrict__ batch, float* __restrict__ cntG) {
    __shared__ int hist[NG];
    for (int i = threadIdx.x; i < NG; i += 256) hist[i] = 0;
    int i = blockIdx.x * 256 + threadIdx.x;
    int lane = threadIdx.x & 63, wv = threadIdx.x >> 6;
    int v = (i < NN) ? cnt[i] : 0;
    if (i < NN) dis[i] = rsqrtf((float)v + 1.0f);
    int s = v;
#pragma unroll
    for (int d = 1; d < 64; d <<= 1) {
        int t = __shfl_up(s, d);
        if (lane >= d) s += t;
    }
    __shared__ int wtot[4];
    if (lane == 63) wtot[wv] = s;
    __syncthreads();
    if (i < NN) atomicAdd(&hist[batch[i]], 1);
    int woff = 0;
    for (int w = 0; w < wv; ++w) woff += wtot[w];
    if (i < NN) rowstart[i] = woff + s - v;
    if (threadIdx.x == 255) bsum[blockIdx.x] = woff + s;
    __syncthreads();
    for (int g = threadIdx.x; g < NG; g += 256)
        if (hist[g]) atomicAdd(&cntG[g], (float)hist[g]);
}

__global__ void k_scan2(const int* __restrict__ bsum, int* __restrict__ boff) {
    int lane = threadIdx.x & 63, wv = threadIdx.x >> 6;
    int v = (threadIdx.x < NB) ? bsum[threadIdx.x] : 0;
    int s = v;
#pragma unroll
    for (int d = 1; d < 64; d <<= 1) {
        int t = __shfl_up(s, d);
        if (lane >= d) s += t;
    }
    __shared__ int wtot[4];
    if (lane == 63) wtot[wv] = s;
    __syncthreads();
    int woff = 0;
    for (int w = 0; w < wv; ++w) woff += wtot[w];
    if (threadIdx.x < NB) boff[threadIdx.x] = woff + s - v;
}

__global__ void k_scan3(int* __restrict__ rowstart, const int* __restrict__ boff,
                        int* __restrict__ cursor) {
    int i = blockIdx.x * 256 + threadIdx.x;
    if (i < NN) {
        int v = rowstart[i] + boff[blockIdx.x];
        rowstart[i] = v;
        cursor[i] = v;
    }
    if (i == 0) rowstart[NN] = NE;
}

// 4B scatter (cheapest dirty-line form)
__global__ void k_fill(const int* __restrict__ src, const int* __restrict__ dst,
                       int* __restrict__ cursor, int* __restrict__ csr_src) {
    int e = blockIdx.x * 256 + threadIdx.x;
    if (e < NE) {
        int pos = atomicAdd(&cursor[dst[e]], 1);
        csr_src[pos] = src[e];
    }
}

// coalesced pack of {src, dis[src]}
__global__ void k_pack(const int* __restrict__ csr_src, const float* __restrict__ dis,
                       int2* __restrict__ pair) {
    int e = blockIdx.x * 256 + threadIdx.x;
    if (e < NE) {
        int s = csr_src[e];
        pair[e] = make_int2(s, __float_as_int(dis[s]));
    }
}

// ---------------- weight conversion ----------------
struct WDesc { const float* s; unsigned short* d; int fin; int fout; };
struct WTable { WDesc w[12]; };

__global__ void k_convw(WTable t) {
    WDesc wd = t.w[blockIdx.x];
    int total = wd.fin * wd.fout;
    for (int i = threadIdx.x; i < total; i += 256) {
        int c = i / wd.fin, k = i % wd.fin;
        wd.d[i] = f2bf(wd.s[(size_t)k * wd.fout + c]);
    }
}

// ---------------- fused level-0 matmul: x(fp32) @ [gcn0|gat0|sWl0|sWr0] ------
// LDS-staged epilogue: coalesced 16B stores into comb sections + sr0.
__global__ __launch_bounds__(256) void k_mm0(
        const float* __restrict__ X, const unsigned short* __restrict__ Wf,
        const float* __restrict__ as_, const float* __restrict__ ad_,
        float* __restrict__ alsrc, float* __restrict__ aldst,
        unsigned short* __restrict__ comb, unsigned short* __restrict__ sr0) {
    constexpr int FIN = 128, NCT = 20;   // FOUT = 320
    __shared__ unsigned short stg[4 * 16 * 320];   // 40KB
    int wave = threadIdx.x >> 6, lane = threadIdx.x & 63;
    int rowbase = (blockIdx.x * 4 + wave) * 16;
    if (rowbase >= NN) return;
    int lr = lane & 15, lg = lane >> 4;
    int arow = rowbase + lr;
    f32x4 acc[NCT] = {};
    const float* xp = X + (size_t)arow * FIN + lg * 8;
#pragma unroll
    for (int k0 = 0; k0 < FIN; k0 += 32) {
        float4 v0 = *(const float4*)(xp + k0);
        float4 v1 = *(const float4*)(xp + k0 + 4);
        u16x8 au;
        au[0] = f2bf(v0.x); au[1] = f2bf(v0.y); au[2] = f2bf(v0.z); au[3] = f2bf(v0.w);
        au[4] = f2bf(v1.x); au[5] = f2bf(v1.y); au[6] = f2bf(v1.z); au[7] = f2bf(v1.w);
        bf16x8 a1 = *(bf16x8*)&au;
#pragma unroll
        for (int ct = 0; ct < NCT; ++ct) {
            int wcol = ct * 16 + lr;
            bf16x8 b1 = *(const bf16x8*)(Wf + (size_t)wcol * FIN + k0 + lg * 8);
            acc[ct] = __builtin_amdgcn_mfma_f32_16x16x32_bf16(a1, b1, acc[ct], 0, 0, 0);
        }
    }
    // GAT attention-logit epilogue on fused cols 64..191
    {
        float ps[2][4] = {}, pd[2][4] = {};
#pragma unroll
        for (int ct = 4; ct < 12; ++ct) {
            int hh = (ct >= 8) ? 1 : 0;
            int colg = ct * 16 + lr - 64;
            float cs = as_[colg], cd = ad_[colg];
#pragma unroll
            for (int j = 0; j < 4; ++j) {
                ps[hh][j] += acc[ct][j] * cs;
                pd[hh][j] += acc[ct][j] * cd;
            }
        }
#pragma unroll
        for (int m = 1; m < 16; m <<= 1)
#pragma unroll
            for (int hh = 0; hh < 2; ++hh)
#pragma unroll
                for (int j = 0; j < 4; ++j) {
                    ps[hh][j] += __shfl_xor(ps[hh][j], m);
                    pd[hh][j] += __shfl_xor(pd[hh][j], m);
                }
        if (lr == 0) {
#pragma unroll
            for (int j = 0; j < 4; ++j) {
                int row = rowbase + lg * 4 + j;
#pragma unroll
                for (int hh = 0; hh < 2; ++hh) {
                    alsrc[(size_t)row * 2 + hh] = ps[hh][j];
                    aldst[(size_t)row * 2 + hh] = pd[hh][j];
                }
            }
        }
    }
    // stage to LDS (wave-private slice), then coalesced 16B stores
    unsigned short* sw = &stg[wave * 16 * 320];
#pragma unroll
    for (int ct = 0; ct < NCT; ++ct) {
        int col = ct * 16 + lr;
#pragma unroll
        for (int j = 0; j < 4; ++j)
            sw[(lg * 4 + j) * 320 + col] = f2bf(acc[ct][j]);
    }
#pragma unroll
    for (int o = lane; o < 16 * 40; o += 64) {
        int r = o / 40, oct = o % 40;
        int c0 = oct * 8;
        u16x8 v = *(u16x8*)&sw[r * 320 + c0];
        size_t gRow = rowbase + r;
        if (oct < 8)       *(u16x8*)&comb[gRow * 256 + c0] = v;               // GCN
        else if (oct < 24) *(u16x8*)&comb[gRow * 256 + 128 + (c0 - 64)] = v;  // GAT
        else if (oct < 32) *(u16x8*)&comb[gRow * 256 + 64 + (c0 - 192)] = v;  // SAGE-L
        else               *(u16x8*)&sr0[gRow * 64 + (c0 - 256)] = v;
    }
}

// ---------------- MFMA matmul, 32 rows/wave, fused BN+act, LDS epilogue ----
template <int FIN, int FOUT, bool DUAL, bool BIAS, int BNACT, int ALH, int OSTR, int OOFF>
__global__ __launch_bounds__(256) void k_mm(
        const unsigned short* __restrict__ A1, const unsigned short* __restrict__ W1t,
        const unsigned short* __restrict__ A2, const unsigned short* __restrict__ W2t,
        const float* __restrict__ bias,
        const float* __restrict__ bns, const float* __restrict__ bng, const float* __restrict__ bnb,
        const float* __restrict__ as_, const float* __restrict__ ad_,
        float* __restrict__ alsrc, float* __restrict__ aldst,
        unsigned short* __restrict__ out) {
    constexpr int NCT = FOUT / 16;
    __shared__ unsigned short stg[4 * 32 * FOUT];   // 16KB (F=64) / 32KB (F=128)
    int wave = threadIdx.x >> 6, lane = threadIdx.x & 63;
    int rowbase = (blockIdx.x * 4 + wave) * 32;
    if (rowbase >= NN) return;
    bool t1 = (rowbase + 16) < NN;          // NN%32==16 -> last wave tile0 only
    int lr = lane & 15, lg = lane >> 4;
    int arow0 = rowbase + lr;
    int arow1 = t1 ? (arow0 + 16) : arow0;
    f32x4 acc0[NCT] = {}, acc1[NCT] = {};
    const unsigned short* a1p0 = A1 + (size_t)arow0 * FIN + lg * 8;
    const unsigned short* a1p1 = A1 + (size_t)arow1 * FIN + lg * 8;
    const unsigned short* a2p0 = DUAL ? (A2 + (size_t)arow0 * FIN + lg * 8) : nullptr;
    const unsigned short* a2p1 = DUAL ? (A2 + (size_t)arow1 * FIN + lg * 8) : nullptr;
#pragma unroll
    for (int k0 = 0; k0 < FIN; k0 += 32) {
        bf16x8 a0, a1v;
        if (BNACT == 0) {
            a0  = *(const bf16x8*)(a1p0 + k0);
            a1v = *(const bf16x8*)(a1p1 + k0);
        } else {
            u16x8 r0v = *(const u16x8*)(a1p0 + k0);
            u16x8 r1v = *(const u16x8*)(a1p1 + k0);
            u16x8 t0, t1v;
#pragma unroll
            for (int j = 0; j < 8; ++j) {
                int f = k0 + lg * 8 + j;
                float mean = bns[f] * (1.0f / NN);
                float var = bns[FIN + f] * (1.0f / NN) - mean * mean;
                float rstd = rsqrtf(var + BN_EPS);
                float g = bng[f], bb = bnb[f];
                float v0 = (bf2f(r0v[j]) - mean) * rstd * g + bb;
                float v1 = (bf2f(r1v[j]) - mean) * rstd * g + bb;
                if (BNACT == 1) { v0 = fmaxf(v0, 0.f); v1 = fmaxf(v1, 0.f); }
                if (BNACT == 2) {
                    v0 = (v0 > 0.f) ? v0 : (__expf(v0) - 1.0f);
                    v1 = (v1 > 0.f) ? v1 : (__expf(v1) - 1.0f);
                }
                t0[j] = f2bf(v0); t1v[j] = f2bf(v1);
            }
            a0 = *(bf16x8*)&t0; a1v = *(bf16x8*)&t1v;
        }
        bf16x8 a20 = {}, a21 = {};
        if (DUAL) { a20 = *(const bf16x8*)(a2p0 + k0); a21 = *(const bf16x8*)(a2p1 + k0); }
#pragma unroll
        for (int ct = 0; ct < NCT; ++ct) {
            int wcol = ct * 16 + lr;
            bf16x8 b1 = *(const bf16x8*)(W1t + (size_t)wcol * FIN + k0 + lg * 8);
            acc0[ct] = __builtin_amdgcn_mfma_f32_16x16x32_bf16(a0, b1, acc0[ct], 0, 0, 0);
            acc1[ct] = __builtin_amdgcn_mfma_f32_16x16x32_bf16(a1v, b1, acc1[ct], 0, 0, 0);
            if (DUAL) {
                bf16x8 b2 = *(const bf16x8*)(W2t + (size_t)wcol * FIN + k0 + lg * 8);
                acc0[ct] = __builtin_amdgcn_mfma_f32_16x16x32_bf16(a20, b2, acc0[ct], 0, 0, 0);
                acc1[ct] = __builtin_amdgcn_mfma_f32_16x16x32_bf16(a21, b2, acc1[ct], 0, 0, 0);
            }
        }
    }
    if (ALH > 0) {
        constexpr int NH = (ALH > 0) ? ALH : 1;
        float ps0[NH][4] = {}, pd0[NH][4] = {}, ps1[NH][4] = {}, pd1[NH][4] = {};
#pragma unroll
        for (int ct = 0; ct < NCT; ++ct) {
            int hh = (ALH == 2 && ct >= NCT / 2) ? 1 : 0;
            int col = ct * 16 + lr;
            float cs = as_[col], cd = ad_[col];
#pragma unroll
            for (int j = 0; j < 4; ++j) {
                ps0[hh][j] += acc0[ct][j] * cs;
                pd0[hh][j] += acc0[ct][j] * cd;
                ps1[hh][j] += acc1[ct][j] * cs;
                pd1[hh][j] += acc1[ct][j] * cd;
            }
        }
#pragma unroll
        for (int m = 1; m < 16; m <<= 1)
#pragma unroll
            for (int hh = 0; hh < NH; ++hh)
#pragma unroll
                for (int j = 0; j < 4; ++j) {
                    ps0[hh][j] += __shfl_xor(ps0[hh][j], m);
                    pd0[hh][j] += __shfl_xor(pd0[hh][j], m);
                    ps1[hh][j] += __shfl_xor(ps1[hh][j], m);
                    pd1[hh][j] += __shfl_xor(pd1[hh][j], m);
                }
        if (lr == 0) {
#pragma unroll
            for (int j = 0; j < 4; ++j) {
                int row = rowbase + lg * 4 + j;
#pragma unroll
                for (int hh = 0; hh < NH; ++hh) {
                    alsrc[(size_t)row * ALH + hh] = ps0[hh][j];
                    aldst[(size_t)row * ALH + hh] = pd0[hh][j];
                    if (t1) {
                        alsrc[(size_t)(row + 16) * ALH + hh] = ps1[hh][j];
                        aldst[(size_t)(row + 16) * ALH + hh] = pd1[hh][j];
                    }
                }
            }
        }
    }
    // stage tile to LDS (wave-private), then coalesced 16B stores
    unsigned short* sw = &stg[wave * 32 * FOUT];
#pragma unroll
    for (int ct = 0; ct < NCT; ++ct) {
        int col = ct * 16 + lr;
        float bv = BIAS ? bias[col] : 0.f;
#pragma unroll
        for (int j = 0; j < 4; ++j) {
            int r = lg * 4 + j;
            sw[r * FOUT + col] = f2bf(acc0[ct][j] + bv);
            sw[(16 + r) * FOUT + col] = f2bf(acc1[ct][j] + bv);
        }
    }
    constexpr int OPR = FOUT / 8;           // octets per row
#pragma unroll
    for (int o = lane; o < 32 * OPR; o += 64) {
        int r = o / OPR, c0 = (o % OPR) * 8;
        if (r < 16 || t1) {
            u16x8 v = *(u16x8*)&sw[r * FOUT + c0];
            *(u16x8*)&out[(size_t)(rowbase + r) * OSTR + OOFF + c0] = v;
        }
    }
}

// ---------------- fused 3-branch aggregation over comb[NN][256] -----------
// r13 config: int2 pair stream, unroll 4, pipelined pair prefetch.
template <int H, bool GATBIAS>
__global__ __launch_bounds__(256) void k_aggf(
        const int* __restrict__ rowstart, const int2* __restrict__ pair,
        const float* __restrict__ dis, const float* __restrict__ alsrc,
        const float* __restrict__ aldst, const unsigned short* __restrict__ comb,
        const float* __restrict__ gat_bias,
        unsigned short* __restrict__ outGCN, unsigned short* __restrict__ outGAT,
        unsigned short* __restrict__ outSAGE) {
    int wave = threadIdx.x >> 6, lane = threadIdx.x & 63;
    int n = blockIdx.x * 4 + wave;
    if (n >= NN) return;
    int eg = lane >> 5, fl = lane & 31;
    int f0 = fl * 8;
    bool isGCN = fl < 8, isSAGE = (fl >= 8) && (fl < 16), isGAT = fl >= 16;
    int hh = (H == 2) ? ((fl >= 24) ? 1 : 0) : 0;
    int r0 = rowstart[n], r1 = rowstart[n + 1];
    float dn = dis[n];
    float adn = isGAT ? aldst[n * H + hh] : 0.f;
    float tself = isGAT ? (alsrc[n * H + hh] + adn) : 0.f;
    tself = (tself >= 0.f) ? tself : 0.2f * tself;
    float wsG = __expf(tself);                       // GAT self weight
    float selfw = isGCN ? dn * dn : (isGAT ? wsG : 0.f);
    float acc[8] = {};
    if (eg == 0) {
        u16x8 hv = *(const u16x8*)&comb[(size_t)n * 256 + f0];
#pragma unroll
        for (int j = 0; j < 8; ++j) acc[j] = selfw * bf2f(hv[j]);
    }
    float dsum = 0.f;
    int e = r0 + eg;
    int2 p = (e < r1) ? pair[e] : make_int2(0, 0);
#pragma unroll 4
    for (; e < r1; e += 2) {
        int en = min(e + 2, r1 - 1);           // clamped prefetch (branchless)
        int2 pn = pair[en];
        int s = p.x;
        float al = isGAT ? alsrc[(size_t)s * H + hh] : 0.f;
        float v = al + adn;
        v = (v >= 0.f) ? v : 0.2f * v;
        float we = __expf(v);
        dsum += we;
        float w = isGCN ? __int_as_float(p.y) * dn : (isGAT ? we : 1.0f);
        u16x8 hs = *(const u16x8*)&comb[(size_t)s * 256 + f0];
#pragma unroll
        for (int jj = 0; jj < 8; ++jj) acc[jj] += w * bf2f(hs[jj]);
        p = pn;
    }
    // GAT denominator (masked butterfly within head cluster + cross-eg)
    if (H == 2) {
        dsum += __shfl_xor(dsum, 1);
        dsum += __shfl_xor(dsum, 2);
        dsum += __shfl_xor(dsum, 4);
        dsum += __shfl_xor(dsum, 32);
        dsum *= 0.125f;
    } else {
        dsum += __shfl_xor(dsum, 1);
        dsum += __shfl_xor(dsum, 2);
        dsum += __shfl_xor(dsum, 4);
        dsum += __shfl_xor(dsum, 8);
        dsum += __shfl_xor(dsum, 32);
        dsum *= 0.0625f;
    }
    float dinv = 1.0f / (wsG + dsum + 1e-16f);
    // feature reduce across the two edge-groups
#pragma unroll
    for (int jj = 0; jj < 8; ++jj) acc[jj] += __shfl_xor(acc[jj], 32);
    if (eg == 0) {
        float inv = 1.0f / fmaxf((float)(r1 - r0), 1.0f);
        float mul = isGCN ? 1.0f : (isSAGE ? inv : dinv);
        u16x8 o;
#pragma unroll
        for (int jj = 0; jj < 8; ++jj) {
            float v = acc[jj] * mul;
            if (GATBIAS && isGAT) v += gat_bias[f0 - 128 + jj];
            o[jj] = f2bf(v);
        }
        if (isGCN)       *(u16x8*)&outGCN[(size_t)n * 64 + f0] = o;
        else if (isSAGE) *(u16x8*)&outSAGE[(size_t)n * 64 + (f0 - 64)] = o;
        else             *(u16x8*)&outGAT[(size_t)n * 128 + (f0 - 128)] = o;
    }
}

// ---------------- fused 3-buffer BatchNorm stats ----------------
template <bool SAGEON, bool TWO>
__global__ void k_bn_stats3(const unsigned short* __restrict__ gcn,
                            const unsigned short* __restrict__ gat,
                            const unsigned short* __restrict__ sage,
                            const unsigned short* __restrict__ sr,
                            float* __restrict__ segG, float* __restrict__ segA,
                            float* __restrict__ segS) {
    __shared__ float lsum[256], lsq[256];
    for (int i = threadIdx.x; i < 256; i += 256) { lsum[i] = 0.f; lsq[i] = 0.f; }
    __syncthreads();
    int oct = threadIdx.x & 31, rl = threadIdx.x >> 5;   // 8 row-lanes
    if (SAGEON || oct < 24) {
        float s[8] = {}, s2[8] = {};
        for (int n = blockIdx.x * 8 + rl; n < NN; n += gridDim.x * 8) {
            u16x8 v;
            if (oct < 8)       v = *(const u16x8*)&gcn[(size_t)n * 64 + oct * 8];
            else if (oct < 24) v = *(const u16x8*)&gat[(size_t)n * 128 + (oct - 8) * 8];
            else               v = *(const u16x8*)&sage[(size_t)n * 64 + (oct - 24) * 8];
            u16x8 w = {};
            if (TWO && oct >= 24) w = *(const u16x8*)&sr[(size_t)n * 64 + (oct - 24) * 8];
#pragma unroll
            for (int j = 0; j < 8; ++j) {
                float f = bf2f(v[j]);
                if (TWO && oct >= 24) f += bf2f(w[j]);
                s[j] += f; s2[j] += f * f;
            }
        }
#pragma unroll
        for (int j = 0; j < 8; ++j) {
            atomicAdd(&lsum[oct * 8 + j], s[j]);
            atomicAdd(&lsq[oct * 8 + j], s2[j]);
        }
    }
    __syncthreads();
    int t = threadIdx.x;
    if (t < 192 || SAGEON) {
        float* base; int f, F;
        if (t < 64)       { base = segG; f = t;       F = 64; }
        else if (t < 192) { base = segA; f = t - 64;  F = 128; }
        else              { base = segS; f = t - 192; F = 64; }
        atomicAdd(&base[f], lsum[t]);
        atomicAdd(&base[F + f], lsq[t]);
    }
}

// ---------------- single-buffer BatchNorm stats (sageM1) -------------------
template <int F, bool TWO>
__global__ void k_bn_stats(const unsigned short* __restrict__ x,
                           const unsigned short* __restrict__ y,
                           float* __restrict__ sums) {
    constexpr int TPR = F / 8;
    constexpr int RPB = 256 / TPR;
    __shared__ float lsum[F], lsq[F];
    for (int i = threadIdx.x; i < F; i += 256) { lsum[i] = 0.f; lsq[i] = 0.f; }
    __syncthreads();
    int fl = threadIdx.x % TPR, rl = threadIdx.x / TPR;
    int f0 = fl * 8;
    float s[8] = {}, s2[8] = {};
    for (int n = blockIdx.x * RPB + rl; n < NN; n += gridDim.x * RPB) {
        u16x8 v = *(const u16x8*)&x[(size_t)n * F + f0];
        u16x8 w = {};
        if (TWO) w = *(const u16x8*)&y[(size_t)n * F + f0];
#pragma unroll
        for (int j = 0; j < 8; ++j) {
            float f = bf2f(v[j]);
            if (TWO) f += bf2f(w[j]);
            s[j] += f; s2[j] += f * f;
        }
    }
#pragma unroll
    for (int off = TPR; off < 64; off <<= 1)
#pragma unroll
        for (int j = 0; j < 8; ++j) { s[j] += __shfl_xor(s[j], off); s2[j] += __shfl_xor(s2[j], off); }
    if ((threadIdx.x & 63) < TPR) {
#pragma unroll
        for (int j = 0; j < 8; ++j) {
            atomicAdd(&lsum[f0 + j], s[j]);
            atomicAdd(&lsq[f0 + j], s2[j]);
        }
    }
    __syncthreads();
    for (int i = threadIdx.x; i < F; i += 256) {
        atomicAdd(&sums[i], lsum[i]);
        atomicAdd(&sums[F + i], lsq[i]);
    }
}

// ---------------- BatchNorm apply, optional dual output --------------------
template <int F, int ACT, bool TWO, bool O1, bool O2, int OOFF>
__global__ void k_bn_apply(const unsigned short* __restrict__ x,
                           const unsigned short* __restrict__ y,
                           const float* __restrict__ sums,
                           const float* __restrict__ gamma, const float* __restrict__ beta,
                           unsigned short* __restrict__ out1, unsigned short* __restrict__ comb) {
    int idx = blockIdx.x * 256 + threadIdx.x;   // units of 8 elems
    if (idx >= NN * F / 8) return;
    int row = idx / (F / 8);
    int f0 = (idx % (F / 8)) * 8;
    u16x8 v = *(const u16x8*)&x[(size_t)idx * 8];
    u16x8 w = {};
    if (TWO) w = *(const u16x8*)&y[(size_t)idx * 8];
    u16x8 o;
#pragma unroll
    for (int j = 0; j < 8; ++j) {
        int f = f0 + j;
        float mean = sums[f] * (1.0f / NN);
        float var = sums[F + f] * (1.0f / NN) - mean * mean;
        float rstd = rsqrtf(var + BN_EPS);
        float raw = bf2f(v[j]);
        if (TWO) raw += bf2f(w[j]);
        float val = (raw - mean) * rstd * gamma[f] + beta[f];
        if (ACT == 1) val = fmaxf(val, 0.f);
        if (ACT == 2) val = (val > 0.f) ? val : (__expf(val) - 1.0f);
        o[j] = f2bf(val);
    }
    if (O1) *(u16x8*)&out1[(size_t)idx * 8] = o;
    if (O2) *(u16x8*)&comb[(size_t)row * 256 + OOFF + f0] = o;
}

// ---------------- pooling (all three branches, one dispatch) ---------------
__global__ void k_pool3(const unsigned short* __restrict__ a,
                        const unsigned short* __restrict__ b,
                        const unsigned short* __restrict__ c,
                        const int* __restrict__ batch, float* __restrict__ pooled) {
    int sel = blockIdx.x / NPB;
    int nb = blockIdx.x % NPB;
    const unsigned short* x = (sel == 0) ? a : ((sel == 1) ? b : c);
    int off = sel * 128;
    int f = threadIdx.x & 127;
    int half = threadIdx.x >> 7;
    int nend = min(NN, (nb + 1) * 128);
    float acc = 0.f; int gcur = -1;
    for (int n = nb * 128 + half; n < nend; n += 2) {
        int g = batch[n];
        if (g != gcur) {
            if (gcur >= 0) atomicAdd(&pooled[(size_t)gcur * 384 + off + f], acc);
            gcur = g; acc = 0.f;
        }
        acc += bf2f(x[(size_t)n * 128 + f]);
    }
    if (gcur >= 0) atomicAdd(&pooled[(size_t)gcur * 384 + off + f], acc);
}

__global__ void k_fusion(const float* __restrict__ pooled, const float* __restrict__ cntG,
                         const float* __restrict__ W, const float* __restrict__ b,
                         float* __restrict__ out) {
    int idx = blockIdx.x * 256 + threadIdx.x;   // NG*128
    if (idx >= NG * 128) return;
    int g = idx / 128, o = idx % 128;
    float inv = 1.0f / fmaxf(cntG[g], 1.0f);
    float acc = b[o];
#pragma unroll 4
    for (int k = 0; k < 384; ++k)
        acc += pooled[g * 384 + k] * inv * W[k * 128 + o];
    out[idx] = acc;
}

// ---------------- launcher ----------------
static inline int grid1(long long n) { return (int)((n + 255) / 256); }

extern "C" void kernel_launch(void* const* d_in, const int* in_sizes, int n_in,
                              void* d_out, int out_size, void* d_ws, size_t ws_size,
                              hipStream_t stream) {
    const float* x       = (const float*)d_in[0];
    const int*   ei      = (const int*)d_in[1];
    const int*   batch   = (const int*)d_in[2];
    const float* gcn_W0  = (const float*)d_in[3];
    const float* gcn_W1  = (const float*)d_in[5];
    const float* gcn_W2  = (const float*)d_in[7];
    const float* gcn_b2  = (const float*)d_in[8];
    const float* gcn_g0  = (const float*)d_in[9];
    const float* gcn_bb0 = (const float*)d_in[10];
    const float* gcn_g1  = (const float*)d_in[11];
    const float* gcn_bb1 = (const float*)d_in[12];
    const float* gat_W0  = (const float*)d_in[13];
    const float* gat_as0 = (const float*)d_in[14];
    const float* gat_ad0 = (const float*)d_in[15];
    const float* gat_W1  = (const float*)d_in[17];
    const float* gat_as1 = (const float*)d_in[18];
    const float* gat_ad1 = (const float*)d_in[19];
    const float* gat_W2  = (const float*)d_in[21];
    const float* gat_as2 = (const float*)d_in[22];
    const float* gat_ad2 = (const float*)d_in[23];
    const float* gat_b2  = (const float*)d_in[24];
    const float* gat_g0  = (const float*)d_in[25];
    const float* gat_bb0 = (const float*)d_in[26];
    const float* gat_g1  = (const float*)d_in[27];
    const float* gat_bb1 = (const float*)d_in[28];
    const float* sage_Wl0 = (const float*)d_in[29];
    const float* sage_Wr0 = (const float*)d_in[30];
    const float* sage_Wl1 = (const float*)d_in[32];
    const float* sage_Wr1 = (const float*)d_in[33];
    const float* sage_Wl2 = (const float*)d_in[35];
    const float* sage_Wr2 = (const float*)d_in[36];
    const float* sage_b2  = (const float*)d_in[37];
    const float* sage_g0  = (const float*)d_in[38];
    const float* sage_bb0 = (const float*)d_in[39];
    const float* sage_g1  = (const float*)d_in[40];
    const float* sage_bb1 = (const float*)d_in[41];
    const float* fus_W    = (const float*)d_in[42];
    const float* fus_b    = (const float*)d_in[43];

    const int* src = ei;
    const int* dst = ei + NE;

    // workspace layout (float units)
    float* ws = (float*)d_ws;
    size_t off = 0;
    auto alloc = [&](size_t n) { float* p = ws + off; off += (n + 3) & ~(size_t)3; return p; };
    unsigned short* combA = (unsigned short*)alloc((size_t)NN * 128);  // NN*256 bf16
    unsigned short* combB = (unsigned short*)alloc((size_t)NN * 128);
    unsigned short* bufGCN  = (unsigned short*)alloc((size_t)NN * 32); // NN*64 bf16
    unsigned short* bufGAT  = (unsigned short*)alloc((size_t)NN * 64); // NN*128 bf16
    unsigned short* bufSAGE = (unsigned short*)alloc((size_t)NN * 32);
    unsigned short* sr0     = (unsigned short*)alloc((size_t)NN * 32);
    unsigned short* sageH0  = (unsigned short*)alloc((size_t)NN * 32);
    unsigned short* sageM1  = (unsigned short*)alloc((size_t)NN * 32);
    unsigned short* wt      = (unsigned short*)alloc(110592 / 2);
    int*   rowstart = (int*)alloc(NN + 1);
    int*   cursor   = (int*)alloc(NN);
    int*   csr_src  = (int*)alloc(NE);
    int2*  pair     = (int2*)alloc((size_t)NE * 2);
    int*   bsum     = (int*)alloc(NB);
    int*   boff     = (int*)alloc(NB);
    float* dis   = alloc(NN);
    float* alsrc = alloc((size_t)NN * 2);
    float* aldst = alloc((size_t)NN * 2);
    // contiguous zero region: bnsum | pooled | cntG | indeg
    float* zr = alloc(6 * 256 + NG * 384 + NG + NN);
    float* bnsum  = zr;
    float* pooled = bnsum + 6 * 256;
    float* cntG   = pooled + NG * 384;
    int*   indeg  = (int*)(cntG + NG);
    (void)ws_size; (void)n_in; (void)in_sizes; (void)out_size;

    unsigned short* sageH1  = sr0;                    // sr0 dead after L0
    unsigned short* finGCN  = combB;                  // combB dead after aggF L1
    unsigned short* finSAGE = combB + (size_t)NN * 128;

    // fused L0 weights [gcn(64)|gat(128)|sWl(64)|sWr(64)] x 128 + per-layer W^T
    unsigned short* wf        = wt;                  // 40960
    unsigned short* gcn_W1t   = wf + 40960;          // 64x64
    unsigned short* gcn_W2t   = gcn_W1t + 4096;      // 64x128
    unsigned short* gat_W1t   = gcn_W2t + 8192;      // 128x128
    unsigned short* gat_W2t   = gat_W1t + 16384;
    unsigned short* sage_Wl1t = gat_W2t + 16384;
    unsigned short* sage_Wr1t = sage_Wl1t + 4096;
    unsigned short* sage_Wl2t = sage_Wr1t + 4096;
    unsigned short* sage_Wr2t = sage_Wl2t + 8192;

    const int gAgg = NN / 4;
    const int gMM  = (NN + 63) / 64;     // k_mm0: 16 rows/wave
    const int gMM2 = (NN + 127) / 128;   // k_mm:  32 rows/wave

    // ---- CSR build + precompute ----
    hipMemsetAsync(zr, 0, (6 * 256 + NG * 384 + NG + NN) * 4, stream);
    k_indeg<<<grid1(NE), 256, 0, stream>>>(dst, indeg);
    k_scan1<<<NB, 256, 0, stream>>>(indeg, rowstart, bsum, dis, batch, cntG);
    k_scan2<<<1, 256, 0, stream>>>(bsum, boff);
    k_scan3<<<NB, 256, 0, stream>>>(rowstart, boff, cursor);
    k_fill<<<grid1(NE), 256, 0, stream>>>(src, dst, cursor, csr_src);
    k_pack<<<grid1(NE), 256, 0, stream>>>(csr_src, dis, pair);
    WTable wtab = {{
        { gcn_W0, wf, 128, 64 }, { gat_W0, wf + 64 * 128, 128, 128 },
        { sage_Wl0, wf + 192 * 128, 128, 64 }, { sage_Wr0, wf + 256 * 128, 128, 64 },
        { gcn_W1, gcn_W1t, 64, 64 }, { gcn_W2, gcn_W2t, 64, 128 },
        { gat_W1, gat_W1t, 128, 128 }, { gat_W2, gat_W2t, 128, 128 },
        { sage_Wl1, sage_Wl1t, 64, 64 }, { sage_Wr1, sage_Wr1t, 64, 64 },
        { sage_Wl2, sage_Wl2t, 64, 128 }, { sage_Wr2, sage_Wr2t, 64, 128 },
    }};
    k_convw<<<12, 256, 0, stream>>>(wtab);

    // ---- L0: fused matmul -> combA; fused agg -> compacts ----
    k_mm0<<<gMM, 256, 0, stream>>>(x, wf, gat_as0, gat_ad0, alsrc, aldst, combA, sr0);
    k_aggf<2, false><<<gAgg, 256, 0, stream>>>(rowstart, pair, dis, alsrc, aldst,
                                               combA, nullptr, bufGCN, bufGAT, bufSAGE);
    k_bn_stats3<true, true><<<250, 256, 0, stream>>>(
        bufGCN, bufGAT, bufSAGE, sr0, bnsum + 0 * 256, bnsum + 2 * 256, bnsum + 4 * 256);
    // L1 producers -> combB
    k_mm<64, 64, false, false, 1, 0, 256, 0><<<gMM2, 256, 0, stream>>>(
        bufGCN, gcn_W1t, nullptr, nullptr, nullptr,
        bnsum + 0 * 256, gcn_g0, gcn_bb0, nullptr, nullptr, nullptr, nullptr, combB);
    k_mm<128, 128, false, false, 2, 2, 256, 128><<<gMM2, 256, 0, stream>>>(
        bufGAT, gat_W1t, nullptr, nullptr, nullptr,
        bnsum + 2 * 256, gat_g0, gat_bb0, gat_as1, gat_ad1, alsrc, aldst, combB);
    k_bn_apply<64, 1, true, true, true, 64><<<grid1(NN * 8), 256, 0, stream>>>(
        bufSAGE, sr0, bnsum + 4 * 256, sage_g0, sage_bb0, sageH0, combB);

    // ---- L1: fused agg ----
    k_aggf<2, false><<<gAgg, 256, 0, stream>>>(rowstart, pair, dis, alsrc, aldst,
                                               combB, nullptr, bufGCN, bufGAT, bufSAGE);
    k_bn_stats3<false, false><<<250, 256, 0, stream>>>(
        bufGCN, bufGAT, nullptr, nullptr, bnsum + 1 * 256, bnsum + 3 * 256, nullptr);
    k_mm<64, 64, true, false, 0, 0, 64, 0><<<gMM2, 256, 0, stream>>>(
        bufSAGE, sage_Wl1t, sageH0, sage_Wr1t, nullptr,
        nullptr, nullptr, nullptr, nullptr, nullptr, nullptr, nullptr, sageM1);
    // L2 producers -> combA
    k_bn_apply<64, 1, false, false, true, 0><<<grid1(NN * 8), 256, 0, stream>>>(
        bufGCN, nullptr, bnsum + 1 * 256, gcn_g1, gcn_bb1, nullptr, combA);
    k_mm<128, 128, false, false, 2, 1, 256, 128><<<gMM2, 256, 0, stream>>>(
        bufGAT, gat_W2t, nullptr, nullptr, nullptr,
        bnsum + 3 * 256, gat_g1, gat_bb1, gat_as2, gat_ad2, alsrc, aldst, combA);
    k_bn_stats<64, false><<<250, 256, 0, stream>>>(sageM1, nullptr, bnsum + 5 * 256);
    k_bn_apply<64, 1, false, true, true, 64><<<grid1(NN * 8), 256, 0, stream>>>(
        sageM1, nullptr, bnsum + 5 * 256, sage_g1, sage_bb1, sageH1, combA);

    // ---- L2: fused agg (GAT H=1, bias fused) ----
    k_aggf<1, true><<<gAgg, 256, 0, stream>>>(rowstart, pair, dis, alsrc, aldst,
                                              combA, gat_b2, bufGCN, bufGAT, bufSAGE);
    k_mm<64, 128, false, true, 0, 0, 128, 0><<<gMM2, 256, 0, stream>>>(
        bufGCN, gcn_W2t, nullptr, nullptr, gcn_b2,
        nullptr, nullptr, nullptr, nullptr, nullptr, nullptr, nullptr, finGCN);
    k_mm<64, 128, true, true, 0, 0, 128, 0><<<gMM2, 256, 0, stream>>>(
        bufSAGE, sage_Wl2t, sageH1, sage_Wr2t, sage_b2,
        nullptr, nullptr, nullptr, nullptr, nullptr, nullptr, nullptr, finSAGE);

    // ---- pool + fusion ----
    k_pool3<<<3 * NPB, 256, 0, stream>>>(finGCN, bufGAT, finSAGE, batch, pooled);
    k_fusion<<<grid1(NG * 128), 256, 0, stream>>>(pooled, cntG, fus_W, fus_b, (float*)d_out);
}